// Round 7
// baseline (294.294 us; speedup 1.0000x reference)
//
#include <hip/hip_runtime.h>
#include <hip/hip_bf16.h>

#define TT 4096
#define CC 1024
#define NHEAD 16
#define DH 64
#define N3C 3072

typedef __attribute__((ext_vector_type(8))) short short8;
typedef __attribute__((ext_vector_type(4))) float floatx4;
typedef __attribute__((ext_vector_type(16))) float floatx16;
typedef __attribute__((ext_vector_type(4))) unsigned int uint4v;

// Q pre-scale: 1/sqrt(64) * log2(e)  (softmax in exp2 domain, m=0 fixed)
#define QSCALE 0.18033688011112042f

__device__ __forceinline__ short f2bf(float f) {
    union { __hip_bfloat16 h; short s; } u;
    u.h = __float2bfloat16(f);
    return u.s;
}

// async global->LDS 16B per lane; LDS dest = wave-uniform base + lane*16
__device__ __forceinline__ void gload_lds16(const void* g, void* l) {
    __builtin_amdgcn_global_load_lds(
        (const __attribute__((address_space(1))) unsigned int*)(unsigned long long)g,
        (__attribute__((address_space(3))) unsigned int*)(unsigned int)(unsigned long long)l,
        16, 0, 0);
}

// pack two fp32 -> bf16x2 by truncation (1 v_perm)
__device__ __forceinline__ unsigned pk_trunc(float lo, float hi) {
    return __builtin_amdgcn_perm(__float_as_uint(hi), __float_as_uint(lo), 0x07060302u);
}

// ---------------- fused prep: cvt x->bf16, transpose both weights ----------------
__device__ __forceinline__ void tr_body(const float* __restrict__ in, short* __restrict__ out,
                                        int K, int N, int bx, int by, int tid, float (*tile)[33]) {
    int nt = bx * 32, kt = by * 32;
    int tx = tid & 31, ty = tid >> 5;
#pragma unroll
    for (int i = 0; i < 32; i += 8)
        tile[ty + i][tx] = in[(size_t)(kt + ty + i) * N + nt + tx];
    __syncthreads();
#pragma unroll
    for (int i = 0; i < 32; i += 8)
        out[(size_t)(nt + ty + i) * K + kt + tx] = f2bf(tile[tx][ty + i]);
}

__global__ void k_prep(const float* __restrict__ x, short* __restrict__ xb,
                       const float* __restrict__ w_qkv, short* __restrict__ wqkvT,
                       const float* __restrict__ w_proj, short* __restrict__ wprojT) {
    __shared__ float tile[32][33];
    int id = blockIdx.x;
    int tid = threadIdx.x;
    if (id < 4096) {
        int i = (id * 256 + tid) * 4;
        float4 v = *(const float4*)&x[i];
        short4 r;
        r.x = f2bf(v.x); r.y = f2bf(v.y); r.z = f2bf(v.z); r.w = f2bf(v.w);
        *(short4*)&xb[i] = r;
    } else if (id < 4096 + 3072) {
        int r = id - 4096;
        tr_body(w_qkv, wqkvT, CC, N3C, r % 96, r / 96, tid, tile);
    } else {
        int r = id - 7168;
        tr_body(w_proj, wprojT, CC, CC, r & 31, r >> 5, tid, tile);
    }
}

// ---------------- GEMM1: qkv = x @ w_qkv + b  (BK=64, two [128][32] sub-buffers) ----
__global__ __launch_bounds__(256) void k_gemm_qkv(const short* __restrict__ A,
                                                  const short* __restrict__ Bt,
                                                  const float* __restrict__ bias,
                                                  short* __restrict__ Q,
                                                  short* __restrict__ Kb,
                                                  short* __restrict__ Vtg) {
    const int m0 = blockIdx.y * 128;
    const int n0 = blockIdx.x * 128;
    __shared__ __attribute__((aligned(16))) short As[2][128 * 32];
    __shared__ __attribute__((aligned(16))) short Bs[2][128 * 32];
    const int tid = threadIdx.x;
    const int lane = tid & 63;
    const int w = tid >> 6;
    const int wm = w >> 1, wn = w & 1;
    const int quad = lane >> 4;
    const int l16 = lane & 15;

    const int r0 = tid >> 2, c0 = (tid & 3) * 8;
    const short* pA[2][2]; const short* pB[2][2];
    short* lA[2][2]; short* lB[2][2];
#pragma unroll
    for (int it = 0; it < 2; ++it)
#pragma unroll
        for (int hh = 0; hh < 2; ++hh) {
            pA[it][hh] = A + (size_t)(m0 + it * 64 + r0) * CC + hh * 32 + c0;
            pB[it][hh] = Bt + (size_t)(n0 + it * 64 + r0) * CC + hh * 32 + c0;
            lA[it][hh] = &As[hh][(it * 256 + w * 64) * 8];
            lB[it][hh] = &Bs[hh][(it * 256 + w * 64) * 8];
        }

    floatx4 acc[4][4] = {};
    for (int kb = 0; kb < CC; kb += 64) {
        __syncthreads();
#pragma unroll
        for (int it = 0; it < 2; ++it)
#pragma unroll
            for (int hh = 0; hh < 2; ++hh) {
                gload_lds16(pA[it][hh] + kb, lA[it][hh]);
                gload_lds16(pB[it][hh] + kb, lB[it][hh]);
            }
        __syncthreads();
#pragma unroll
        for (int kk = 0; kk < 2; ++kk) {
            short8 af[4], bf[4];
#pragma unroll
            for (int mi = 0; mi < 4; ++mi)
                af[mi] = *(const short8*)&As[kk][(wm * 64 + mi * 16 + l16) * 32 + quad * 8];
#pragma unroll
            for (int ni = 0; ni < 4; ++ni)
                bf[ni] = *(const short8*)&Bs[kk][(wn * 64 + ni * 16 + l16) * 32 + quad * 8];
#pragma unroll
            for (int mi = 0; mi < 4; ++mi)
#pragma unroll
                for (int ni = 0; ni < 4; ++ni)
                    acc[mi][ni] = __builtin_amdgcn_mfma_f32_16x16x32_bf16(af[mi], bf[ni], acc[mi][ni], 0, 0, 0);
        }
    }
#pragma unroll
    for (int mi = 0; mi < 4; ++mi) {
#pragma unroll
        for (int ni = 0; ni < 4; ++ni) {
            int gm = m0 + wm * 64 + mi * 16 + quad * 4;
            int gn = n0 + wn * 64 + ni * 16 + l16;
            int which = gn >> 10;
            int cc = gn & 1023;
            int h = cc >> 6, d = cc & 63;
            float bv = bias[gn];
            if (which == 0) {
#pragma unroll
                for (int r = 0; r < 4; ++r) {
                    float v = (acc[mi][ni][r] + bv) * QSCALE;
                    Q[((size_t)h * TT + (gm + r)) * DH + d] = f2bf(v);
                }
            } else if (which == 1) {
#pragma unroll
                for (int r = 0; r < 4; ++r) {
                    float v = acc[mi][ni][r] + bv;
                    Kb[((size_t)h * TT + (gm + r)) * DH + d] = f2bf(v);
                }
            } else {
                short4 vv;
                vv.x = f2bf(acc[mi][ni][0] + bv);
                vv.y = f2bf(acc[mi][ni][1] + bv);
                vv.z = f2bf(acc[mi][ni][2] + bv);
                vv.w = f2bf(acc[mi][ni][3] + bv);
                *(short4*)&Vtg[((size_t)h * DH + d) * TT + gm] = vv;
            }
        }
    }
}

// ---------------- flash attention v12: reg-only P + k-parity wave pair + prefetch --
// R6 lesson: 1-wave blocks = 8 waves/CU cap + un-pipelined loop -> 2600cy/step
// (latency-bound; MfmaUtil 9.9, VALU 21, occ 14). Per-step math kept identical
// (harness-verified): swapped QK^T via mfma_32x32x16 (S^T[k][q], q=lane&31,
// k-rows (r&3)+8(r>>2)+4hi), T12 pk+permlane32_swap relayout, V^T rows as PV
// B-operand, zero in-loop LDS/barriers.
//
// Fix 1 (parallelism): 2 waves/block, wave w takes k-steps ki%2==w. 4096 waves
// -> 16/CU; critical chain 128->64 steps; K/V L2 traffic UNCHANGED (k-steps
// partitioned). Partials additive (fixed-max exp2 domain): one 8KB LDS exchange
// + single __syncthreads at the end.
// Fix 2 (latency): cross-iteration K prefetch (akn for the wave's next step,
// issued before QK/softmax/PV ~500+cy of cover); V loads at step top covered by
// QK+softmax. NO barrier in the loop -> compiler's counted vmcnt keeps loads in
// flight (the thing R2/R3's __syncthreads drained).
//
// Grid 16x128, bid = h+16y: h in low bits -> per-XCD L2 head affinity (R1).
// y->u map (u = 32-row strip id, heavy first): y<64: u=127-2y; else u=2(y-64).
// Every CU's 8 resident blocks sum to exactly 516 steps, each CU has one
// ~64-step critical block -> uniform finish.
__global__ __launch_bounds__(128) void k_attn(const short* __restrict__ Qh,
                                              const short* __restrict__ Kh,
                                              const short* __restrict__ VhT,
                                              short* __restrict__ Ob) {
    const int h = blockIdx.x;
    const int y = blockIdx.y;                 // 0..127
    const int u = (y < 64) ? (127 - 2 * y) : (2 * (y - 64));
    const int qb = u * 32;                    // first q row of this block's strip
    const int nk = u + 1;                     // 32-wide k-steps

    const int tid = threadIdx.x;
    const int w = tid >> 6;                   // k-parity of this wave
    const int lane = tid & 63;
    const int l31 = lane & 31;
    const int hi = lane >> 5;

    __shared__ float pO[32][64];              // wave1 partial O
    __shared__ float pl[32];                  // wave1 partial l

    const short* Qp = Qh + (size_t)h * TT * DH;
    const short* Kp = Kh + (size_t)h * TT * DH;
    const short* Vp = VhT + (size_t)h * DH * TT;

    // Q B-frags (persistent): B[d-rows][q=l31], 8 consecutive d per lane
    short8 bq[4];
#pragma unroll
    for (int st = 0; st < 4; ++st)
        bq[st] = *(const short8*)&Qp[(size_t)(qb + l31) * DH + st * 16 + hi * 8];

    floatx16 accO0 = {}, accO1 = {};
    float l_acc = 0.f;

    // prologue: K frags for this wave's first step (ki = w)
    short8 ak[4];
    if (w < nk) {
#pragma unroll
        for (int st = 0; st < 4; ++st)
            ak[st] = *(const short8*)&Kp[(size_t)(w * 32 + l31) * DH + st * 16 + hi * 8];
    }

    for (int ki = w; ki < nk; ki += 2) {
        const int k0 = ki * 32;
        const bool masked = (ki == nk - 1);

        // V frags for CURRENT step — covered by QK^T + softmax (~500cy)
        short8 vf[2][2];
#pragma unroll
        for (int db = 0; db < 2; ++db)
#pragma unroll
            for (int kst = 0; kst < 2; ++kst)
                vf[db][kst] = *(const short8*)&Vp[(size_t)(db * 32 + l31) * TT + k0 + kst * 16 + hi * 8];

        // K prefetch for the wave's NEXT step (ki+2) — full iteration of cover
        short8 akn[4];
        const bool more = (ki + 2 < nk);
        if (more) {
            const int kn = k0 + 64;
#pragma unroll
            for (int st = 0; st < 4; ++st)
                akn[st] = *(const short8*)&Kp[(size_t)(kn + l31) * DH + st * 16 + hi * 8];
        }

        // S^T[32k][32q] = K . Q^T  (4 d-steps of 16); ak prefetched -> no stall
        floatx16 s = {};
#pragma unroll
        for (int st = 0; st < 4; ++st)
            s = __builtin_amdgcn_mfma_f32_32x32x16_bf16(ak[st], bq[st], s, 0, 0, 0);

        // softmax (m=0, exp2 domain); lane holds k-rows (r&3)+8(r>>2)+4hi, q=l31
        float p[16];
#pragma unroll
        for (int r = 0; r < 16; ++r)
            p[r] = __builtin_amdgcn_exp2f(s[r]);
        if (masked) {
            const int qg = qb + l31;
#pragma unroll
            for (int r = 0; r < 16; ++r) {
                int kg = k0 + (r & 3) + 8 * (r >> 2) + 4 * hi;
                p[r] = (kg <= qg) ? p[r] : 0.f;
            }
        }
        // tree-sum into l (shallow dependency chain)
        {
            float t0 = (p[0] + p[1]) + (p[2] + p[3]);
            float t1 = (p[4] + p[5]) + (p[6] + p[7]);
            float t2 = (p[8] + p[9]) + (p[10] + p[11]);
            float t3 = (p[12] + p[13]) + (p[14] + p[15]);
            l_acc += (t0 + t1) + (t2 + t3);
        }

        // T12 relayout: D-layout -> PV A-operand (P[q=l31][k 8-consec])
        unsigned pa[8];
        pa[0] = pk_trunc(p[0], p[1]);   pa[1] = pk_trunc(p[2], p[3]);
        pa[2] = pk_trunc(p[4], p[5]);   pa[3] = pk_trunc(p[6], p[7]);
        pa[4] = pk_trunc(p[8], p[9]);   pa[5] = pk_trunc(p[10], p[11]);
        pa[6] = pk_trunc(p[12], p[13]); pa[7] = pk_trunc(p[14], p[15]);
        asm("v_permlane32_swap_b32 %0, %1" : "+v"(pa[0]), "+v"(pa[2]));
        asm("v_permlane32_swap_b32 %0, %1" : "+v"(pa[1]), "+v"(pa[3]));
        asm("v_permlane32_swap_b32 %0, %1" : "+v"(pa[4]), "+v"(pa[6]));
        asm("v_permlane32_swap_b32 %0, %1" : "+v"(pa[5]), "+v"(pa[7]));
        uint4v a0v = {pa[0], pa[1], pa[2], pa[3]};   // k 0..15
        uint4v a1v = {pa[4], pa[5], pa[6], pa[7]};   // k 16..31
        short8 A0 = __builtin_bit_cast(short8, a0v);
        short8 A1 = __builtin_bit_cast(short8, a1v);

        // O[32q][64d] += P V   (2 d-blocks x 2 k-steps)
        accO0 = __builtin_amdgcn_mfma_f32_32x32x16_bf16(A0, vf[0][0], accO0, 0, 0, 0);
        accO0 = __builtin_amdgcn_mfma_f32_32x32x16_bf16(A1, vf[0][1], accO0, 0, 0, 0);
        accO1 = __builtin_amdgcn_mfma_f32_32x32x16_bf16(A0, vf[1][0], accO1, 0, 0, 0);
        accO1 = __builtin_amdgcn_mfma_f32_32x32x16_bf16(A1, vf[1][1], accO1, 0, 0, 0);

        if (more) {
#pragma unroll
            for (int st = 0; st < 4; ++st) ak[st] = akn[st];
        }
    }

    // intra-wave l: halves (hi=0/1) hold complementary k-rows for q=l31
    l_acc += __shfl_xor(l_acc, 32, 64);

    // cross-wave combine (additive partials, one barrier total)
    if (w == 1) {
#pragma unroll
        for (int r = 0; r < 16; ++r) {
            int qr = (r & 3) + 8 * (r >> 2) + 4 * hi;
            pO[qr][l31]      = accO0[r];
            pO[qr][32 + l31] = accO1[r];
        }
        if (lane < 32) pl[lane] = l_acc;
    }
    __syncthreads();
    if (w == 0) {
#pragma unroll
        for (int r = 0; r < 16; ++r) {
            int qr = (r & 3) + 8 * (r >> 2) + 4 * hi;
            accO0[r] += pO[qr][l31];
            accO1[r] += pO[qr][32 + l31];
        }
        l_acc += pl[l31];
        float inv = __builtin_amdgcn_rcpf(l_acc);
#pragma unroll
        for (int r = 0; r < 16; ++r) {
            int qr = (r & 3) + 8 * (r >> 2) + 4 * hi;
            float iv = __shfl(inv, qr, 64);
            int qg = qb + qr;
            Ob[(size_t)qg * CC + h * DH + l31]      = f2bf(accO0[r] * iv);
            Ob[(size_t)qg * CC + h * DH + 32 + l31] = f2bf(accO1[r] * iv);
        }
    }
}

// ---------------- GEMM2: out = Ob @ w_proj + b (fp32 out, BK=64) ----------------
__global__ __launch_bounds__(256) void k_gemm_proj(const short* __restrict__ A,
                                                   const short* __restrict__ Bt,
                                                   const float* __restrict__ bias,
                                                   float* __restrict__ out) {
    const int m0 = blockIdx.y * 128;
    const int n0 = blockIdx.x * 128;
    __shared__ __attribute__((aligned(16))) short As[2][128 * 32];
    __shared__ __attribute__((aligned(16))) short Bs[2][128 * 32];
    const int tid = threadIdx.x;
    const int lane = tid & 63;
    const int w = tid >> 6;
    const int wm = w >> 1, wn = w & 1;
    const int quad = lane >> 4;
    const int l16 = lane & 15;

    const int r0 = tid >> 2, c0 = (tid & 3) * 8;
    const short* pA[2][2]; const short* pB[2][2];
    short* lA[2][2]; short* lB[2][2];
#pragma unroll
    for (int it = 0; it < 2; ++it)
#pragma unroll
        for (int hh = 0; hh < 2; ++hh) {
            pA[it][hh] = A + (size_t)(m0 + it * 64 + r0) * CC + hh * 32 + c0;
            pB[it][hh] = Bt + (size_t)(n0 + it * 64 + r0) * CC + hh * 32 + c0;
            lA[it][hh] = &As[hh][(it * 256 + w * 64) * 8];
            lB[it][hh] = &Bs[hh][(it * 256 + w * 64) * 8];
        }

    floatx4 acc[4][4] = {};
    for (int kb = 0; kb < CC; kb += 64) {
        __syncthreads();
#pragma unroll
        for (int it = 0; it < 2; ++it)
#pragma unroll
            for (int hh = 0; hh < 2; ++hh) {
                gload_lds16(pA[it][hh] + kb, lA[it][hh]);
                gload_lds16(pB[it][hh] + kb, lB[it][hh]);
            }
        __syncthreads();
#pragma unroll
        for (int kk = 0; kk < 2; ++kk) {
            short8 af[4], bf[4];
#pragma unroll
            for (int mi = 0; mi < 4; ++mi)
                af[mi] = *(const short8*)&As[kk][(wm * 64 + mi * 16 + l16) * 32 + quad * 8];
#pragma unroll
            for (int ni = 0; ni < 4; ++ni)
                bf[ni] = *(const short8*)&Bs[kk][(wn * 64 + ni * 16 + l16) * 32 + quad * 8];
#pragma unroll
            for (int mi = 0; mi < 4; ++mi)
#pragma unroll
                for (int ni = 0; ni < 4; ++ni)
                    acc[mi][ni] = __builtin_amdgcn_mfma_f32_16x16x32_bf16(af[mi], bf[ni], acc[mi][ni], 0, 0, 0);
        }
    }
#pragma unroll
    for (int mi = 0; mi < 4; ++mi) {
#pragma unroll
        for (int ni = 0; ni < 4; ++ni) {
            int gm = m0 + wm * 64 + mi * 16 + quad * 4;
            int gn = n0 + wn * 64 + ni * 16 + l16;
            float bv = bias[gn];
#pragma unroll
            for (int r = 0; r < 4; ++r)
                out[(size_t)(gm + r) * CC + gn] = acc[mi][ni][r] + bv;
        }
    }
}

extern "C" void kernel_launch(void* const* d_in, const int* in_sizes, int n_in,
                              void* d_out, int out_size, void* d_ws, size_t ws_size,
                              hipStream_t stream) {
    const float* x      = (const float*)d_in[0];
    const float* w_qkv  = (const float*)d_in[1];
    const float* b_qkv  = (const float*)d_in[2];
    const float* w_proj = (const float*)d_in[3];
    const float* b_proj = (const float*)d_in[4];
    float* out = (float*)d_out;
    char* ws = (char*)d_ws;

    short* xb     = (short*)(ws);                       // 8388608 B
    short* wqkvT  = (short*)(ws + 8388608);             // 6291456 B
    short* wprojT = (short*)(ws + 14680064);            // 2097152 B
    short* Qh     = (short*)(ws + 16777216);            // 8388608 B
    short* Kh     = (short*)(ws + 25165824);
    short* VhT    = (short*)(ws + 33554432);            // [H,64,T]
    short* Ob     = (short*)(ws + 41943040);
    // total 50331648 B (48 MB)

    k_prep<<<8192, 256, 0, stream>>>(x, xb, w_qkv, wqkvT, w_proj, wprojT);
    k_gemm_qkv<<<dim3(N3C / 128, TT / 128), 256, 0, stream>>>(xb, wqkvT, b_qkv, Qh, Kh, VhT);
    k_attn<<<dim3(NHEAD, 128), 128, 0, stream>>>(Qh, Kh, VhT, Ob);
    k_gemm_proj<<<dim3(CC / 128, TT / 128), 256, 0, stream>>>(Ob, wprojT, b_proj, out);
}

// Round 8
// 214.291 us; speedup vs baseline: 1.3733x; 1.3733x over previous
//
#include <hip/hip_runtime.h>
#include <hip/hip_bf16.h>

#define TT 4096
#define CC 1024
#define NHEAD 16
#define DH 64
#define N3C 3072

typedef __attribute__((ext_vector_type(8))) short short8;
typedef __attribute__((ext_vector_type(4))) float floatx4;

// Q pre-scale: 1/sqrt(64) * log2(e)  (softmax in exp2 domain, m=0 fixed)
#define QSCALE 0.18033688011112042f

__device__ __forceinline__ short f2bf(float f) {
    union { __hip_bfloat16 h; short s; } u;
    u.h = __float2bfloat16(f);
    return u.s;
}

// async global->LDS 16B per lane; LDS dest = wave-uniform base + lane*16
__device__ __forceinline__ void gload_lds16(const void* g, void* l) {
    __builtin_amdgcn_global_load_lds(
        (const __attribute__((address_space(1))) unsigned int*)(unsigned long long)g,
        (__attribute__((address_space(3))) unsigned int*)(unsigned int)(unsigned long long)l,
        16, 0, 0);
}

// pack two fp32 -> bf16x2 by truncation (1 v_perm)
__device__ __forceinline__ unsigned pk_trunc(float lo, float hi) {
    return __builtin_amdgcn_perm(__float_as_uint(hi), __float_as_uint(lo), 0x07060302u);
}

// ---------------- fused prep: cvt x->bf16, transpose both weights ----------------
__device__ __forceinline__ void tr_body(const float* __restrict__ in, short* __restrict__ out,
                                        int K, int N, int bx, int by, int tid, float (*tile)[33]) {
    int nt = bx * 32, kt = by * 32;
    int tx = tid & 31, ty = tid >> 5;
#pragma unroll
    for (int i = 0; i < 32; i += 8)
        tile[ty + i][tx] = in[(size_t)(kt + ty + i) * N + nt + tx];
    __syncthreads();
#pragma unroll
    for (int i = 0; i < 32; i += 8)
        out[(size_t)(nt + ty + i) * K + kt + tx] = f2bf(tile[tx][ty + i]);
}

__global__ void k_prep(const float* __restrict__ x, short* __restrict__ xb,
                       const float* __restrict__ w_qkv, short* __restrict__ wqkvT,
                       const float* __restrict__ w_proj, short* __restrict__ wprojT) {
    __shared__ float tile[32][33];
    int id = blockIdx.x;
    int tid = threadIdx.x;
    if (id < 4096) {
        int i = (id * 256 + tid) * 4;
        float4 v = *(const float4*)&x[i];
        short4 r;
        r.x = f2bf(v.x); r.y = f2bf(v.y); r.z = f2bf(v.z); r.w = f2bf(v.w);
        *(short4*)&xb[i] = r;
    } else if (id < 4096 + 3072) {
        int r = id - 4096;
        tr_body(w_qkv, wqkvT, CC, N3C, r % 96, r / 96, tid, tile);
    } else {
        int r = id - 7168;
        tr_body(w_proj, wprojT, CC, CC, r & 31, r >> 5, tid, tile);
    }
}

// ---------------- GEMM1: qkv = x @ w_qkv + b  (BK=64, two [128][32] sub-buffers) ----
__global__ __launch_bounds__(256) void k_gemm_qkv(const short* __restrict__ A,
                                                  const short* __restrict__ Bt,
                                                  const float* __restrict__ bias,
                                                  short* __restrict__ Q,
                                                  short* __restrict__ Kb,
                                                  short* __restrict__ Vtg) {
    const int m0 = blockIdx.y * 128;
    const int n0 = blockIdx.x * 128;
    __shared__ __attribute__((aligned(16))) short As[2][128 * 32];
    __shared__ __attribute__((aligned(16))) short Bs[2][128 * 32];
    const int tid = threadIdx.x;
    const int lane = tid & 63;
    const int w = tid >> 6;
    const int wm = w >> 1, wn = w & 1;
    const int quad = lane >> 4;
    const int l16 = lane & 15;

    const int r0 = tid >> 2, c0 = (tid & 3) * 8;
    const short* pA[2][2]; const short* pB[2][2];
    short* lA[2][2]; short* lB[2][2];
#pragma unroll
    for (int it = 0; it < 2; ++it)
#pragma unroll
        for (int hh = 0; hh < 2; ++hh) {
            pA[it][hh] = A + (size_t)(m0 + it * 64 + r0) * CC + hh * 32 + c0;
            pB[it][hh] = Bt + (size_t)(n0 + it * 64 + r0) * CC + hh * 32 + c0;
            lA[it][hh] = &As[hh][(it * 256 + w * 64) * 8];
            lB[it][hh] = &Bs[hh][(it * 256 + w * 64) * 8];
        }

    floatx4 acc[4][4] = {};
    for (int kb = 0; kb < CC; kb += 64) {
        __syncthreads();
#pragma unroll
        for (int it = 0; it < 2; ++it)
#pragma unroll
            for (int hh = 0; hh < 2; ++hh) {
                gload_lds16(pA[it][hh] + kb, lA[it][hh]);
                gload_lds16(pB[it][hh] + kb, lB[it][hh]);
            }
        __syncthreads();
#pragma unroll
        for (int kk = 0; kk < 2; ++kk) {
            short8 af[4], bf[4];
#pragma unroll
            for (int mi = 0; mi < 4; ++mi)
                af[mi] = *(const short8*)&As[kk][(wm * 64 + mi * 16 + l16) * 32 + quad * 8];
#pragma unroll
            for (int ni = 0; ni < 4; ++ni)
                bf[ni] = *(const short8*)&Bs[kk][(wn * 64 + ni * 16 + l16) * 32 + quad * 8];
#pragma unroll
            for (int mi = 0; mi < 4; ++mi)
#pragma unroll
                for (int ni = 0; ni < 4; ++ni)
                    acc[mi][ni] = __builtin_amdgcn_mfma_f32_16x16x32_bf16(af[mi], bf[ni], acc[mi][ni], 0, 0, 0);
        }
    }
#pragma unroll
    for (int mi = 0; mi < 4; ++mi) {
#pragma unroll
        for (int ni = 0; ni < 4; ++ni) {
            int gm = m0 + wm * 64 + mi * 16 + quad * 4;
            int gn = n0 + wn * 64 + ni * 16 + l16;
            int which = gn >> 10;
            int cc = gn & 1023;
            int h = cc >> 6, d = cc & 63;
            float bv = bias[gn];
            if (which == 0) {
#pragma unroll
                for (int r = 0; r < 4; ++r) {
                    float v = (acc[mi][ni][r] + bv) * QSCALE;
                    Q[((size_t)h * TT + (gm + r)) * DH + d] = f2bf(v);
                }
            } else if (which == 1) {
#pragma unroll
                for (int r = 0; r < 4; ++r) {
                    float v = acc[mi][ni][r] + bv;
                    Kb[((size_t)h * TT + (gm + r)) * DH + d] = f2bf(v);
                }
            } else {
                short4 vv;
                vv.x = f2bf(acc[mi][ni][0] + bv);
                vv.y = f2bf(acc[mi][ni][1] + bv);
                vv.z = f2bf(acc[mi][ni][2] + bv);
                vv.w = f2bf(acc[mi][ni][3] + bv);
                *(short4*)&Vtg[((size_t)h * DH + d) * TT + gm] = vv;
            }
        }
    }
}

// ---------------- flash attention v13: R3 body, two paired tiles per block --------
// R3 is the best measured attn (77.5us). Its one counter-confirmed loss is the
// OCCUPANCY TAIL: blocks have nk in {1..32} iters; light blocks retire early and
// heavy ones finish near-bare (time-weighted 6.5/32 waves vs 16/32 cap; VGPR=92
// caps 16 waves/CU so residency can't be raised). R1 broke XCD affinity, R5's
// split-k added 9.4GB partial traffic - both regressed.
//
// Zero-cost tail fix: nk(qi)+nk(63-qi) = 33 for EVERY qi. Block y runs tile
// (63-y) then tile (y) SEQUENTIALLY with the R3 body verbatim -> every block is
// exactly 33 iterations. Grid (16,32) = 512 blocks = 2/CU, uniform finish:
// flat 8 waves/CU for the whole dispatch instead of 16 decaying to 4.
// bid = h + 16*y keeps bid%8 = h%8 -> per-XCD L2 head affinity intact (R1).
// Seam safety: the epilogue's two __syncthreads separate tile-1 Ps reads from
// tile-2 Ps writes; tile-2's first in-loop barrier convoys any fast wave.
// No partials, no extra traffic, in-loop body unchanged from R3 (verified).
__device__ __forceinline__ void attn_tile(const short* __restrict__ Qp,
                                          const short* __restrict__ Kp,
                                          const short* __restrict__ Vp,
                                          short* __restrict__ Ob,
                                          int h, int qi,
                                          int tid, int lane, int w, int quad, int l16,
                                          short* __restrict__ Ps0,
                                          float (*wl)[64], float* lsum) {
    const int q0 = qi * 64;
    const int nk = (qi >> 1) + 1;

    short8 aq[4][2];
#pragma unroll
    for (int qg = 0; qg < 4; ++qg)
#pragma unroll
        for (int ss = 0; ss < 2; ++ss)
            aq[qg][ss] = *(const short8*)&Qp[(size_t)(q0 + qg * 16 + l16) * DH + ss * 32 + quad * 8];

    floatx4 accO[4] = {};
    float l_part[4] = {0.f, 0.f, 0.f, 0.f};
    int buf = 0;

    // prologue: K fragments for ki=0 (wave's k-strip [w*32,+32))
    short8 kf[2][2];
#pragma unroll
    for (int mi = 0; mi < 2; ++mi)
#pragma unroll
        for (int ss = 0; ss < 2; ++ss)
            kf[mi][ss] = *(const short8*)&Kp[(size_t)(w * 32 + mi * 16 + l16) * DH + ss * 32 + quad * 8];

    for (int ki = 0; ki < nk; ++ki) {
        const int k0 = ki * 128;
        const bool masked = (ki == nk - 1);

        // S^T strips: D[k][q], lane: k = w*32+mi*16+quad*4+r, q = qg*16+l16
        floatx4 accS[2][4] = {};
        __builtin_amdgcn_s_setprio(1);
#pragma unroll
        for (int mi = 0; mi < 2; ++mi)
#pragma unroll
            for (int ss = 0; ss < 2; ++ss)
#pragma unroll
                for (int qg = 0; qg < 4; ++qg)
                    accS[mi][qg] = __builtin_amdgcn_mfma_f32_16x16x32_bf16(kf[mi][ss], aq[qg][ss], accS[mi][qg], 0, 0, 0);
        __builtin_amdgcn_s_setprio(0);

        // softmax (m=0, exp2 domain) + pack -> Ps
        short* Pb = Ps0 + buf * (64 * 136);
#pragma unroll
        for (int mi = 0; mi < 2; ++mi) {
            const int kbase = k0 + w * 32 + mi * 16 + quad * 4;
#pragma unroll
            for (int qg = 0; qg < 4; ++qg) {
                float pv[4];
#pragma unroll
                for (int r = 0; r < 4; ++r) {
                    float e = __builtin_amdgcn_exp2f(accS[mi][qg][r]);
                    if (masked)
                        e = (kbase + r <= q0 + qg * 16 + l16) ? e : 0.f;
                    pv[r] = e;
                    l_part[qg] += e;
                }
                uint2 pk;
                pk.x = pk_trunc(pv[0], pv[1]);
                pk.y = pk_trunc(pv[2], pv[3]);
                *(uint2*)&Pb[(qg * 16 + l16) * 136 + w * 32 + mi * 16 + quad * 4] = pk;
            }
        }

        // V fragments (d-strip [w*16,+16)) — wave-private; counted vmcnt wait
        short8 vf[4];
#pragma unroll
        for (int ks = 0; ks < 4; ++ks)
            vf[ks] = *(const short8*)&Vp[(size_t)(w * 16 + l16) * TT + k0 + ks * 32 + quad * 8];

        // K prefetch for ki+1 — issued AFTER vf (vmcnt drains oldest-first)
        short8 kfn[2][2];
        if (ki + 1 < nk) {
            const int kn0 = k0 + 128;
#pragma unroll
            for (int mi = 0; mi < 2; ++mi)
#pragma unroll
                for (int ss = 0; ss < 2; ++ss)
                    kfn[mi][ss] = *(const short8*)&Kp[(size_t)(kn0 + w * 32 + mi * 16 + l16) * DH + ss * 32 + quad * 8];
        }

        // barrier WITHOUT vmcnt drain (only Ps ds_writes must be visible)
        asm volatile("s_waitcnt lgkmcnt(0)" ::: "memory");
        __builtin_amdgcn_s_barrier();
        asm volatile("" ::: "memory");

        // O[q][d-strip] += P V
        __builtin_amdgcn_s_setprio(1);
#pragma unroll
        for (int qg = 0; qg < 4; ++qg)
#pragma unroll
            for (int ks = 0; ks < 4; ++ks) {
                short8 ap = *(const short8*)&Pb[(qg * 16 + l16) * 136 + ks * 32 + quad * 8];
                accO[qg] = __builtin_amdgcn_mfma_f32_16x16x32_bf16(ap, vf[ks], accO[qg], 0, 0, 0);
            }
        __builtin_amdgcn_s_setprio(0);

#pragma unroll
        for (int mi = 0; mi < 2; ++mi)
#pragma unroll
            for (int ss = 0; ss < 2; ++ss)
                kf[mi][ss] = kfn[mi][ss];
        buf ^= 1;
    }

    // reduce l: lane holds partials for q = qg*16+l16 (over its 8 k-rows)
#pragma unroll
    for (int qg = 0; qg < 4; ++qg) {
        float lr = l_part[qg];
        lr += __shfl_xor(lr, 16, 64);
        lr += __shfl_xor(lr, 32, 64);
        if (lane < 16) wl[w][qg * 16 + lane] = lr;
    }
    __syncthreads();
    if (tid < 64) lsum[tid] = wl[0][tid] + wl[1][tid] + wl[2][tid] + wl[3][tid];
    __syncthreads();

    // epilogue: lane holds O[q = qg*16+quad*4+r][d = w*16+l16]
#pragma unroll
    for (int qg = 0; qg < 4; ++qg) {
#pragma unroll
        for (int r = 0; r < 4; ++r) {
            int q = qg * 16 + quad * 4 + r;
            float o = accO[qg][r] / lsum[q];
            Ob[(size_t)(q0 + q) * CC + h * DH + w * 16 + l16] = f2bf(o);
        }
    }
}

__global__ __launch_bounds__(256) void k_attn(const short* __restrict__ Qh,
                                              const short* __restrict__ Kh,
                                              const short* __restrict__ VhT,
                                              short* __restrict__ Ob) {
    const int h = blockIdx.x;
    const int y = blockIdx.y;          // 0..31; tiles (63-y) + (y): 33 iters total
    const int tid = threadIdx.x, lane = tid & 63, w = tid >> 6;
    const int quad = lane >> 4, l16 = lane & 15;

    __shared__ __attribute__((aligned(16))) short Ps[2][64 * 136];
    __shared__ float wl[4][64];
    __shared__ float lsum[64];

    const short* Qp = Qh + (size_t)h * TT * DH;
    const short* Kp = Kh + (size_t)h * TT * DH;
    const short* Vp = VhT + (size_t)h * DH * TT;

    attn_tile(Qp, Kp, Vp, Ob, h, 63 - y, tid, lane, w, quad, l16, &Ps[0][0], wl, lsum);
    attn_tile(Qp, Kp, Vp, Ob, h, y,      tid, lane, w, quad, l16, &Ps[0][0], wl, lsum);
}

// ---------------- GEMM2: out = Ob @ w_proj + b (fp32 out, BK=64) ----------------
__global__ __launch_bounds__(256) void k_gemm_proj(const short* __restrict__ A,
                                                   const short* __restrict__ Bt,
                                                   const float* __restrict__ bias,
                                                   float* __restrict__ out) {
    const int m0 = blockIdx.y * 128;
    const int n0 = blockIdx.x * 128;
    __shared__ __attribute__((aligned(16))) short As[2][128 * 32];
    __shared__ __attribute__((aligned(16))) short Bs[2][128 * 32];
    const int tid = threadIdx.x;
    const int lane = tid & 63;
    const int w = tid >> 6;
    const int wm = w >> 1, wn = w & 1;
    const int quad = lane >> 4;
    const int l16 = lane & 15;

    const int r0 = tid >> 2, c0 = (tid & 3) * 8;
    const short* pA[2][2]; const short* pB[2][2];
    short* lA[2][2]; short* lB[2][2];
#pragma unroll
    for (int it = 0; it < 2; ++it)
#pragma unroll
        for (int hh = 0; hh < 2; ++hh) {
            pA[it][hh] = A + (size_t)(m0 + it * 64 + r0) * CC + hh * 32 + c0;
            pB[it][hh] = Bt + (size_t)(n0 + it * 64 + r0) * CC + hh * 32 + c0;
            lA[it][hh] = &As[hh][(it * 256 + w * 64) * 8];
            lB[it][hh] = &Bs[hh][(it * 256 + w * 64) * 8];
        }

    floatx4 acc[4][4] = {};
    for (int kb = 0; kb < CC; kb += 64) {
        __syncthreads();
#pragma unroll
        for (int it = 0; it < 2; ++it)
#pragma unroll
            for (int hh = 0; hh < 2; ++hh) {
                gload_lds16(pA[it][hh] + kb, lA[it][hh]);
                gload_lds16(pB[it][hh] + kb, lB[it][hh]);
            }
        __syncthreads();
#pragma unroll
        for (int kk = 0; kk < 2; ++kk) {
            short8 af[4], bf[4];
#pragma unroll
            for (int mi = 0; mi < 4; ++mi)
                af[mi] = *(const short8*)&As[kk][(wm * 64 + mi * 16 + l16) * 32 + quad * 8];
#pragma unroll
            for (int ni = 0; ni < 4; ++ni)
                bf[ni] = *(const short8*)&Bs[kk][(wn * 64 + ni * 16 + l16) * 32 + quad * 8];
#pragma unroll
            for (int mi = 0; mi < 4; ++mi)
#pragma unroll
                for (int ni = 0; ni < 4; ++ni)
                    acc[mi][ni] = __builtin_amdgcn_mfma_f32_16x16x32_bf16(af[mi], bf[ni], acc[mi][ni], 0, 0, 0);
        }
    }
#pragma unroll
    for (int mi = 0; mi < 4; ++mi) {
#pragma unroll
        for (int ni = 0; ni < 4; ++ni) {
            int gm = m0 + wm * 64 + mi * 16 + quad * 4;
            int gn = n0 + wn * 64 + ni * 16 + l16;
            float bv = bias[gn];
#pragma unroll
            for (int r = 0; r < 4; ++r)
                out[(size_t)(gm + r) * CC + gn] = acc[mi][ni][r] + bv;
        }
    }
}

extern "C" void kernel_launch(void* const* d_in, const int* in_sizes, int n_in,
                              void* d_out, int out_size, void* d_ws, size_t ws_size,
                              hipStream_t stream) {
    const float* x      = (const float*)d_in[0];
    const float* w_qkv  = (const float*)d_in[1];
    const float* b_qkv  = (const float*)d_in[2];
    const float* w_proj = (const float*)d_in[3];
    const float* b_proj = (const float*)d_in[4];
    float* out = (float*)d_out;
    char* ws = (char*)d_ws;

    short* xb     = (short*)(ws);                       // 8388608 B
    short* wqkvT  = (short*)(ws + 8388608);             // 6291456 B
    short* wprojT = (short*)(ws + 14680064);            // 2097152 B
    short* Qh     = (short*)(ws + 16777216);            // 8388608 B
    short* Kh     = (short*)(ws + 25165824);
    short* VhT    = (short*)(ws + 33554432);            // [H,64,T]
    short* Ob     = (short*)(ws + 41943040);
    // total 50331648 B (48 MB)

    k_prep<<<8192, 256, 0, stream>>>(x, xb, w_qkv, wqkvT, w_proj, wprojT);
    k_gemm_qkv<<<dim3(N3C / 128, TT / 128), 256, 0, stream>>>(xb, wqkvT, b_qkv, Qh, Kh, VhT);
    k_attn<<<dim3(NHEAD, 32), 256, 0, stream>>>(Qh, Kh, VhT, Ob);
    k_gemm_proj<<<dim3(CC / 128, TT / 128), 256, 0, stream>>>(Ob, wprojT, b_proj, out);
}

// Round 9
// 210.248 us; speedup vs baseline: 1.3997x; 1.0192x over previous
//
#include <hip/hip_runtime.h>
#include <hip/hip_bf16.h>

#define TT 4096
#define CC 1024
#define NHEAD 16
#define DH 64
#define N3C 3072

typedef __attribute__((ext_vector_type(8))) short short8;
typedef __attribute__((ext_vector_type(4))) float floatx4;

// Q pre-scale: 1/sqrt(64) * log2(e)  (softmax in exp2 domain, m=0 fixed)
#define QSCALE 0.18033688011112042f

__device__ __forceinline__ short f2bf(float f) {
    union { __hip_bfloat16 h; short s; } u;
    u.h = __float2bfloat16(f);
    return u.s;
}

// async global->LDS 16B per lane; LDS dest = wave-uniform base + lane*16
__device__ __forceinline__ void gload_lds16(const void* g, void* l) {
    __builtin_amdgcn_global_load_lds(
        (const __attribute__((address_space(1))) unsigned int*)(unsigned long long)g,
        (__attribute__((address_space(3))) unsigned int*)(unsigned int)(unsigned long long)l,
        16, 0, 0);
}

// pack two fp32 -> bf16x2 by truncation (1 v_perm)
__device__ __forceinline__ unsigned pk_trunc(float lo, float hi) {
    return __builtin_amdgcn_perm(__float_as_uint(hi), __float_as_uint(lo), 0x07060302u);
}

// ---------------- fused prep: cvt x->bf16, transpose both weights ----------------
__device__ __forceinline__ void tr_body(const float* __restrict__ in, short* __restrict__ out,
                                        int K, int N, int bx, int by, int tid, float (*tile)[33]) {
    int nt = bx * 32, kt = by * 32;
    int tx = tid & 31, ty = tid >> 5;
#pragma unroll
    for (int i = 0; i < 32; i += 8)
        tile[ty + i][tx] = in[(size_t)(kt + ty + i) * N + nt + tx];
    __syncthreads();
#pragma unroll
    for (int i = 0; i < 32; i += 8)
        out[(size_t)(nt + ty + i) * K + kt + tx] = f2bf(tile[tx][ty + i]);
}

__global__ void k_prep(const float* __restrict__ x, short* __restrict__ xb,
                       const float* __restrict__ w_qkv, short* __restrict__ wqkvT,
                       const float* __restrict__ w_proj, short* __restrict__ wprojT) {
    __shared__ float tile[32][33];
    int id = blockIdx.x;
    int tid = threadIdx.x;
    if (id < 4096) {
        int i = (id * 256 + tid) * 4;
        float4 v = *(const float4*)&x[i];
        short4 r;
        r.x = f2bf(v.x); r.y = f2bf(v.y); r.z = f2bf(v.z); r.w = f2bf(v.w);
        *(short4*)&xb[i] = r;
    } else if (id < 4096 + 3072) {
        int r = id - 4096;
        tr_body(w_qkv, wqkvT, CC, N3C, r % 96, r / 96, tid, tile);
    } else {
        int r = id - 7168;
        tr_body(w_proj, wprojT, CC, CC, r & 31, r >> 5, tid, tile);
    }
}

// ---------------- GEMM1: qkv = x @ w_qkv + b  (BK=64, two [128][32] sub-buffers) ----
__global__ __launch_bounds__(256) void k_gemm_qkv(const short* __restrict__ A,
                                                  const short* __restrict__ Bt,
                                                  const float* __restrict__ bias,
                                                  short* __restrict__ Q,
                                                  short* __restrict__ Kb,
                                                  short* __restrict__ Vtg) {
    const int m0 = blockIdx.y * 128;
    const int n0 = blockIdx.x * 128;
    __shared__ __attribute__((aligned(16))) short As[2][128 * 32];
    __shared__ __attribute__((aligned(16))) short Bs[2][128 * 32];
    const int tid = threadIdx.x;
    const int lane = tid & 63;
    const int w = tid >> 6;
    const int wm = w >> 1, wn = w & 1;
    const int quad = lane >> 4;
    const int l16 = lane & 15;

    const int r0 = tid >> 2, c0 = (tid & 3) * 8;
    const short* pA[2][2]; const short* pB[2][2];
    short* lA[2][2]; short* lB[2][2];
#pragma unroll
    for (int it = 0; it < 2; ++it)
#pragma unroll
        for (int hh = 0; hh < 2; ++hh) {
            pA[it][hh] = A + (size_t)(m0 + it * 64 + r0) * CC + hh * 32 + c0;
            pB[it][hh] = Bt + (size_t)(n0 + it * 64 + r0) * CC + hh * 32 + c0;
            lA[it][hh] = &As[hh][(it * 256 + w * 64) * 8];
            lB[it][hh] = &Bs[hh][(it * 256 + w * 64) * 8];
        }

    floatx4 acc[4][4] = {};
    for (int kb = 0; kb < CC; kb += 64) {
        __syncthreads();
#pragma unroll
        for (int it = 0; it < 2; ++it)
#pragma unroll
            for (int hh = 0; hh < 2; ++hh) {
                gload_lds16(pA[it][hh] + kb, lA[it][hh]);
                gload_lds16(pB[it][hh] + kb, lB[it][hh]);
            }
        __syncthreads();
#pragma unroll
        for (int kk = 0; kk < 2; ++kk) {
            short8 af[4], bf[4];
#pragma unroll
            for (int mi = 0; mi < 4; ++mi)
                af[mi] = *(const short8*)&As[kk][(wm * 64 + mi * 16 + l16) * 32 + quad * 8];
#pragma unroll
            for (int ni = 0; ni < 4; ++ni)
                bf[ni] = *(const short8*)&Bs[kk][(wn * 64 + ni * 16 + l16) * 32 + quad * 8];
#pragma unroll
            for (int mi = 0; mi < 4; ++mi)
#pragma unroll
                for (int ni = 0; ni < 4; ++ni)
                    acc[mi][ni] = __builtin_amdgcn_mfma_f32_16x16x32_bf16(af[mi], bf[ni], acc[mi][ni], 0, 0, 0);
        }
    }
#pragma unroll
    for (int mi = 0; mi < 4; ++mi) {
#pragma unroll
        for (int ni = 0; ni < 4; ++ni) {
            int gm = m0 + wm * 64 + mi * 16 + quad * 4;
            int gn = n0 + wn * 64 + ni * 16 + l16;
            int which = gn >> 10;
            int cc = gn & 1023;
            int h = cc >> 6, d = cc & 63;
            float bv = bias[gn];
            if (which == 0) {
#pragma unroll
                for (int r = 0; r < 4; ++r) {
                    float v = (acc[mi][ni][r] + bv) * QSCALE;
                    Q[((size_t)h * TT + (gm + r)) * DH + d] = f2bf(v);
                }
            } else if (which == 1) {
#pragma unroll
                for (int r = 0; r < 4; ++r) {
                    float v = acc[mi][ni][r] + bv;
                    Kb[((size_t)h * TT + (gm + r)) * DH + d] = f2bf(v);
                }
            } else {
                short4 vv;
                vv.x = f2bf(acc[mi][ni][0] + bv);
                vv.y = f2bf(acc[mi][ni][1] + bv);
                vv.z = f2bf(acc[mi][ni][2] + bv);
                vv.w = f2bf(acc[mi][ni][3] + bv);
                *(short4*)&Vtg[((size_t)h * DH + d) * TT + gm] = vv;
            }
        }
    }
}

// ---------------- flash attention v13: R3 body, two paired tiles per block --------
// PLATEAU ACCEPTED at ~78us: R3 (4 blk/CU decaying) == R8 (2 blk/CU flat) ->
// per-CU throughput saturates at ~6.5 waves' worth; per-iteration serial latency
// is the limit and extra resident blocks don't hide it. Three structural
// families (pipelined 4-wave R2/R3, register-only 1/2-wave R6/R7, paired R8)
// converge here or regress. Keeping R8's flat-profile pairing (equal to R3,
// guaranteed uniform finish). DO NOT permute head<->block mapping (R1: per-XCD
// L2 head affinity is worth ~15%).
__device__ __forceinline__ void attn_tile(const short* __restrict__ Qp,
                                          const short* __restrict__ Kp,
                                          const short* __restrict__ Vp,
                                          short* __restrict__ Ob,
                                          int h, int qi,
                                          int tid, int lane, int w, int quad, int l16,
                                          short* __restrict__ Ps0,
                                          float (*wl)[64], float* lsum) {
    const int q0 = qi * 64;
    const int nk = (qi >> 1) + 1;

    short8 aq[4][2];
#pragma unroll
    for (int qg = 0; qg < 4; ++qg)
#pragma unroll
        for (int ss = 0; ss < 2; ++ss)
            aq[qg][ss] = *(const short8*)&Qp[(size_t)(q0 + qg * 16 + l16) * DH + ss * 32 + quad * 8];

    floatx4 accO[4] = {};
    float l_part[4] = {0.f, 0.f, 0.f, 0.f};
    int buf = 0;

    // prologue: K fragments for ki=0 (wave's k-strip [w*32,+32))
    short8 kf[2][2];
#pragma unroll
    for (int mi = 0; mi < 2; ++mi)
#pragma unroll
        for (int ss = 0; ss < 2; ++ss)
            kf[mi][ss] = *(const short8*)&Kp[(size_t)(w * 32 + mi * 16 + l16) * DH + ss * 32 + quad * 8];

    for (int ki = 0; ki < nk; ++ki) {
        const int k0 = ki * 128;
        const bool masked = (ki == nk - 1);

        // S^T strips: D[k][q], lane: k = w*32+mi*16+quad*4+r, q = qg*16+l16
        floatx4 accS[2][4] = {};
        __builtin_amdgcn_s_setprio(1);
#pragma unroll
        for (int mi = 0; mi < 2; ++mi)
#pragma unroll
            for (int ss = 0; ss < 2; ++ss)
#pragma unroll
                for (int qg = 0; qg < 4; ++qg)
                    accS[mi][qg] = __builtin_amdgcn_mfma_f32_16x16x32_bf16(kf[mi][ss], aq[qg][ss], accS[mi][qg], 0, 0, 0);
        __builtin_amdgcn_s_setprio(0);

        // softmax (m=0, exp2 domain) + pack -> Ps
        short* Pb = Ps0 + buf * (64 * 136);
#pragma unroll
        for (int mi = 0; mi < 2; ++mi) {
            const int kbase = k0 + w * 32 + mi * 16 + quad * 4;
#pragma unroll
            for (int qg = 0; qg < 4; ++qg) {
                float pv[4];
#pragma unroll
                for (int r = 0; r < 4; ++r) {
                    float e = __builtin_amdgcn_exp2f(accS[mi][qg][r]);
                    if (masked)
                        e = (kbase + r <= q0 + qg * 16 + l16) ? e : 0.f;
                    pv[r] = e;
                    l_part[qg] += e;
                }
                uint2 pk;
                pk.x = pk_trunc(pv[0], pv[1]);
                pk.y = pk_trunc(pv[2], pv[3]);
                *(uint2*)&Pb[(qg * 16 + l16) * 136 + w * 32 + mi * 16 + quad * 4] = pk;
            }
        }

        // V fragments (d-strip [w*16,+16)) — wave-private; counted vmcnt wait
        short8 vf[4];
#pragma unroll
        for (int ks = 0; ks < 4; ++ks)
            vf[ks] = *(const short8*)&Vp[(size_t)(w * 16 + l16) * TT + k0 + ks * 32 + quad * 8];

        // K prefetch for ki+1 — issued AFTER vf (vmcnt drains oldest-first)
        short8 kfn[2][2];
        if (ki + 1 < nk) {
            const int kn0 = k0 + 128;
#pragma unroll
            for (int mi = 0; mi < 2; ++mi)
#pragma unroll
                for (int ss = 0; ss < 2; ++ss)
                    kfn[mi][ss] = *(const short8*)&Kp[(size_t)(kn0 + w * 32 + mi * 16 + l16) * DH + ss * 32 + quad * 8];
        }

        // barrier WITHOUT vmcnt drain (only Ps ds_writes must be visible)
        asm volatile("s_waitcnt lgkmcnt(0)" ::: "memory");
        __builtin_amdgcn_s_barrier();
        asm volatile("" ::: "memory");

        // O[q][d-strip] += P V
        __builtin_amdgcn_s_setprio(1);
#pragma unroll
        for (int qg = 0; qg < 4; ++qg)
#pragma unroll
            for (int ks = 0; ks < 4; ++ks) {
                short8 ap = *(const short8*)&Pb[(qg * 16 + l16) * 136 + ks * 32 + quad * 8];
                accO[qg] = __builtin_amdgcn_mfma_f32_16x16x32_bf16(ap, vf[ks], accO[qg], 0, 0, 0);
            }
        __builtin_amdgcn_s_setprio(0);

#pragma unroll
        for (int mi = 0; mi < 2; ++mi)
#pragma unroll
            for (int ss = 0; ss < 2; ++ss)
                kf[mi][ss] = kfn[mi][ss];
        buf ^= 1;
    }

    // reduce l: lane holds partials for q = qg*16+l16 (over its 8 k-rows)
#pragma unroll
    for (int qg = 0; qg < 4; ++qg) {
        float lr = l_part[qg];
        lr += __shfl_xor(lr, 16, 64);
        lr += __shfl_xor(lr, 32, 64);
        if (lane < 16) wl[w][qg * 16 + lane] = lr;
    }
    __syncthreads();
    if (tid < 64) lsum[tid] = wl[0][tid] + wl[1][tid] + wl[2][tid] + wl[3][tid];
    __syncthreads();

    // epilogue: lane holds O[q = qg*16+quad*4+r][d = w*16+l16]
#pragma unroll
    for (int qg = 0; qg < 4; ++qg) {
#pragma unroll
        for (int r = 0; r < 4; ++r) {
            int q = qg * 16 + quad * 4 + r;
            float o = accO[qg][r] / lsum[q];
            Ob[(size_t)(q0 + q) * CC + h * DH + w * 16 + l16] = f2bf(o);
        }
    }
}

__global__ __launch_bounds__(256) void k_attn(const short* __restrict__ Qh,
                                              const short* __restrict__ Kh,
                                              const short* __restrict__ VhT,
                                              short* __restrict__ Ob) {
    const int h = blockIdx.x;
    const int y = blockIdx.y;          // 0..31; tiles (63-y) + (y): 33 iters total
    const int tid = threadIdx.x, lane = tid & 63, w = tid >> 6;
    const int quad = lane >> 4, l16 = lane & 15;

    __shared__ __attribute__((aligned(16))) short Ps[2][64 * 136];
    __shared__ float wl[4][64];
    __shared__ float lsum[64];

    const short* Qp = Qh + (size_t)h * TT * DH;
    const short* Kp = Kh + (size_t)h * TT * DH;
    const short* Vp = VhT + (size_t)h * DH * TT;

    attn_tile(Qp, Kp, Vp, Ob, h, 63 - y, tid, lane, w, quad, l16, &Ps[0][0], wl, lsum);
    attn_tile(Qp, Kp, Vp, Ob, h, y,      tid, lane, w, quad, l16, &Ps[0][0], wl, lsum);
}

// ---------------- GEMM2 v2: out = Ob @ w_proj + b, 64x128 tiles -------------------
// R9 change: old grid (8,32)=256 blocks = exactly 1 block/CU (12.5% occupancy
// cap) — the per-K-step global_load_lds drain was fully exposed with no
// co-resident block to overlap (m97-structure needs ~3 blk/CU; m102 shape curve
// says a few hundred TF at N=1024). New: BM=64 -> grid (8,64)=512 blocks =
// 2/CU, LDS 24KB, acc[4][2] (lower VGPR). Same staging/MFMA/epilogue pattern.
// Wave layout: 4 waves = 4 N-strips of 32; each wave computes 64(M)x32(N).
__global__ __launch_bounds__(256) void k_gemm_proj(const short* __restrict__ A,
                                                   const short* __restrict__ Bt,
                                                   const float* __restrict__ bias,
                                                   float* __restrict__ out) {
    const int m0 = blockIdx.y * 64;
    const int n0 = blockIdx.x * 128;
    __shared__ __attribute__((aligned(16))) short As[2][64 * 32];
    __shared__ __attribute__((aligned(16))) short Bs[2][128 * 32];
    const int tid = threadIdx.x;
    const int lane = tid & 63;
    const int w = tid >> 6;
    const int quad = lane >> 4;
    const int l16 = lane & 15;

    const int r0 = tid >> 2, c0 = (tid & 3) * 8;
    const short* pA[2]; const short* pB[2][2];
    short* lA[2]; short* lB[2][2];
#pragma unroll
    for (int hh = 0; hh < 2; ++hh) {
        pA[hh] = A + (size_t)(m0 + r0) * CC + hh * 32 + c0;
        lA[hh] = &As[hh][w * 512];
#pragma unroll
        for (int it = 0; it < 2; ++it) {
            pB[it][hh] = Bt + (size_t)(n0 + it * 64 + r0) * CC + hh * 32 + c0;
            lB[it][hh] = &Bs[hh][(it * 256 + w * 64) * 8];
        }
    }

    floatx4 acc[4][2] = {};
    for (int kb = 0; kb < CC; kb += 64) {
        __syncthreads();
#pragma unroll
        for (int hh = 0; hh < 2; ++hh) {
            gload_lds16(pA[hh] + kb, lA[hh]);
#pragma unroll
            for (int it = 0; it < 2; ++it)
                gload_lds16(pB[it][hh] + kb, lB[it][hh]);
        }
        __syncthreads();
#pragma unroll
        for (int kk = 0; kk < 2; ++kk) {
            short8 af[4], bf[2];
#pragma unroll
            for (int mi = 0; mi < 4; ++mi)
                af[mi] = *(const short8*)&As[kk][(mi * 16 + l16) * 32 + quad * 8];
#pragma unroll
            for (int ni = 0; ni < 2; ++ni)
                bf[ni] = *(const short8*)&Bs[kk][(w * 32 + ni * 16 + l16) * 32 + quad * 8];
#pragma unroll
            for (int mi = 0; mi < 4; ++mi)
#pragma unroll
                for (int ni = 0; ni < 2; ++ni)
                    acc[mi][ni] = __builtin_amdgcn_mfma_f32_16x16x32_bf16(af[mi], bf[ni], acc[mi][ni], 0, 0, 0);
        }
    }
#pragma unroll
    for (int mi = 0; mi < 4; ++mi) {
#pragma unroll
        for (int ni = 0; ni < 2; ++ni) {
            int gm = m0 + mi * 16 + quad * 4;
            int gn = n0 + w * 32 + ni * 16 + l16;
            float bv = bias[gn];
#pragma unroll
            for (int r = 0; r < 4; ++r)
                out[(size_t)(gm + r) * CC + gn] = acc[mi][ni][r] + bv;
        }
    }
}

extern "C" void kernel_launch(void* const* d_in, const int* in_sizes, int n_in,
                              void* d_out, int out_size, void* d_ws, size_t ws_size,
                              hipStream_t stream) {
    const float* x      = (const float*)d_in[0];
    const float* w_qkv  = (const float*)d_in[1];
    const float* b_qkv  = (const float*)d_in[2];
    const float* w_proj = (const float*)d_in[3];
    const float* b_proj = (const float*)d_in[4];
    float* out = (float*)d_out;
    char* ws = (char*)d_ws;

    short* xb     = (short*)(ws);                       // 8388608 B
    short* wqkvT  = (short*)(ws + 8388608);             // 6291456 B
    short* wprojT = (short*)(ws + 14680064);            // 2097152 B
    short* Qh     = (short*)(ws + 16777216);            // 8388608 B
    short* Kh     = (short*)(ws + 25165824);
    short* VhT    = (short*)(ws + 33554432);            // [H,64,T]
    short* Ob     = (short*)(ws + 41943040);
    // total 50331648 B (48 MB)

    k_prep<<<8192, 256, 0, stream>>>(x, xb, w_qkv, wqkvT, w_proj, wprojT);
    k_gemm_qkv<<<dim3(N3C / 128, TT / 128), 256, 0, stream>>>(xb, wqkvT, b_qkv, Qh, Kh, VhT);
    k_attn<<<dim3(NHEAD, 32), 256, 0, stream>>>(Qh, Kh, VhT, Ob);
    k_gemm_proj<<<dim3(CC / 128, TT / 64), 256, 0, stream>>>(Ob, wprojT, b_proj, out);
}

// Round 10
// 207.945 us; speedup vs baseline: 1.4152x; 1.0111x over previous
//
#include <hip/hip_runtime.h>
#include <hip/hip_bf16.h>

#define TT 4096
#define CC 1024
#define NHEAD 16
#define DH 64
#define N3C 3072

typedef __attribute__((ext_vector_type(8))) short short8;
typedef __attribute__((ext_vector_type(4))) float floatx4;
typedef __attribute__((ext_vector_type(4))) unsigned int uint4v;

// Q pre-scale: 1/sqrt(64) * log2(e)  (softmax in exp2 domain, m=0 fixed)
#define QSCALE 0.18033688011112042f

__device__ __forceinline__ short f2bf(float f) {
    union { __hip_bfloat16 h; short s; } u;
    u.h = __float2bfloat16(f);
    return u.s;
}

// async global->LDS 16B per lane; LDS dest = wave-uniform base + lane*16
__device__ __forceinline__ void gload_lds16(const void* g, void* l) {
    __builtin_amdgcn_global_load_lds(
        (const __attribute__((address_space(1))) unsigned int*)(unsigned long long)g,
        (__attribute__((address_space(3))) unsigned int*)(unsigned int)(unsigned long long)l,
        16, 0, 0);
}

// pack two fp32 -> bf16x2 by truncation (1 v_perm) — used only for attn P
__device__ __forceinline__ unsigned pk_trunc(float lo, float hi) {
    return __builtin_amdgcn_perm(__float_as_uint(hi), __float_as_uint(lo), 0x07060302u);
}

// pack two fp32 -> bf16x2 with RNE rounding (numerics identical to f2bf path)
__device__ __forceinline__ unsigned pk_rne(float lo, float hi) {
    unsigned a = (unsigned short)f2bf(lo);
    unsigned b = (unsigned short)f2bf(hi);
    return a | (b << 16);
}

// ---------------- fused prep: cvt x->bf16, transpose both weights ----------------
__device__ __forceinline__ void tr_body(const float* __restrict__ in, short* __restrict__ out,
                                        int K, int N, int bx, int by, int tid, float (*tile)[33]) {
    int nt = bx * 32, kt = by * 32;
    int tx = tid & 31, ty = tid >> 5;
#pragma unroll
    for (int i = 0; i < 32; i += 8)
        tile[ty + i][tx] = in[(size_t)(kt + ty + i) * N + nt + tx];
    __syncthreads();
#pragma unroll
    for (int i = 0; i < 32; i += 8)
        out[(size_t)(nt + ty + i) * K + kt + tx] = f2bf(tile[tx][ty + i]);
}

__global__ void k_prep(const float* __restrict__ x, short* __restrict__ xb,
                       const float* __restrict__ w_qkv, short* __restrict__ wqkvT,
                       const float* __restrict__ w_proj, short* __restrict__ wprojT) {
    __shared__ float tile[32][33];
    int id = blockIdx.x;
    int tid = threadIdx.x;
    if (id < 4096) {
        int i = (id * 256 + tid) * 4;
        float4 v = *(const float4*)&x[i];
        short4 r;
        r.x = f2bf(v.x); r.y = f2bf(v.y); r.z = f2bf(v.z); r.w = f2bf(v.w);
        *(short4*)&xb[i] = r;
    } else if (id < 4096 + 3072) {
        int r = id - 4096;
        tr_body(w_qkv, wqkvT, CC, N3C, r % 96, r / 96, tid, tile);
    } else {
        int r = id - 7168;
        tr_body(w_proj, wprojT, CC, CC, r & 31, r >> 5, tid, tile);
    }
}

// ---------------- GEMM1 v2: qkv = x @ w_qkv + b, LDS re-layout epilogue -----------
// R10 change: the old epilogue scattered Q/K as 32B segments (50% write eff,
// 64 scalar 2B stores/thread) and V^T as 8B chunks at 8KB stride (12.5% eff ->
// V's 8MB became ~64MB effective write traffic). The m97-structure reference
// (874 TF, same main loop) stores contiguous rows — the epilogue is GEMM1's
// unique defect. Fix: after the K-loop the 32KB staging LDS is dead = exactly
// one 128x128 bf16 tile. acc -> LDS (XOR swizzle byte^=(row&7)<<4, <=2-way
// conflicts), barrier, then 16B/lane coalesced stores in the TARGET layout:
// [m][n] tile for Q/K (128B segments per (h,t) row), [n][m] tile for V ((h,d)
// rows along t, 256B segments). which = n0>>10 is block-uniform (no divergence).
__global__ __launch_bounds__(256) void k_gemm_qkv(const short* __restrict__ A,
                                                  const short* __restrict__ Bt,
                                                  const float* __restrict__ bias,
                                                  short* __restrict__ Q,
                                                  short* __restrict__ Kb,
                                                  short* __restrict__ Vtg) {
    const int m0 = blockIdx.y * 128;
    const int n0 = blockIdx.x * 128;
    __shared__ __attribute__((aligned(16))) short Sbuf[4][128 * 32];  // As=0/1, Bs=2/3
    const int tid = threadIdx.x;
    const int lane = tid & 63;
    const int w = tid >> 6;
    const int wm = w >> 1, wn = w & 1;
    const int quad = lane >> 4;
    const int l16 = lane & 15;

    const int r0 = tid >> 2, c0 = (tid & 3) * 8;
    const short* pA[2][2]; const short* pB[2][2];
    short* lA[2][2]; short* lB[2][2];
#pragma unroll
    for (int it = 0; it < 2; ++it)
#pragma unroll
        for (int hh = 0; hh < 2; ++hh) {
            pA[it][hh] = A + (size_t)(m0 + it * 64 + r0) * CC + hh * 32 + c0;
            pB[it][hh] = Bt + (size_t)(n0 + it * 64 + r0) * CC + hh * 32 + c0;
            lA[it][hh] = &Sbuf[hh][(it * 256 + w * 64) * 8];
            lB[it][hh] = &Sbuf[2 + hh][(it * 256 + w * 64) * 8];
        }

    floatx4 acc[4][4] = {};
    for (int kb = 0; kb < CC; kb += 64) {
        __syncthreads();
#pragma unroll
        for (int it = 0; it < 2; ++it)
#pragma unroll
            for (int hh = 0; hh < 2; ++hh) {
                gload_lds16(pA[it][hh] + kb, lA[it][hh]);
                gload_lds16(pB[it][hh] + kb, lB[it][hh]);
            }
        __syncthreads();
#pragma unroll
        for (int kk = 0; kk < 2; ++kk) {
            short8 af[4], bf[4];
#pragma unroll
            for (int mi = 0; mi < 4; ++mi)
                af[mi] = *(const short8*)&Sbuf[kk][(wm * 64 + mi * 16 + l16) * 32 + quad * 8];
#pragma unroll
            for (int ni = 0; ni < 4; ++ni)
                bf[ni] = *(const short8*)&Sbuf[2 + kk][(wn * 64 + ni * 16 + l16) * 32 + quad * 8];
#pragma unroll
            for (int mi = 0; mi < 4; ++mi)
#pragma unroll
                for (int ni = 0; ni < 4; ++ni)
                    acc[mi][ni] = __builtin_amdgcn_mfma_f32_16x16x32_bf16(af[mi], bf[ni], acc[mi][ni], 0, 0, 0);
        }
    }

    // ---- epilogue: acc -> LDS tile (swizzled) -> coalesced 16B stores ----
    __syncthreads();                    // staging LDS dead; safe to reuse
    char* T = (char*)&Sbuf[0][0];
    const int which = n0 >> 10;         // block-uniform: 0=Q, 1=K, 2=V

    if (which < 2) {
        // tile [m][n] bf16, row = 256B; phys = m*256 + ((n*2) ^ ((m&7)<<4))
        const float sc = (which == 0) ? QSCALE : 1.0f;
#pragma unroll
        for (int mi = 0; mi < 4; ++mi)
#pragma unroll
            for (int ni = 0; ni < 4; ++ni) {
                int nl = wn * 64 + ni * 16 + l16;
                float bv = bias[n0 + nl];
#pragma unroll
                for (int r = 0; r < 4; ++r) {
                    int ml = wm * 64 + mi * 16 + quad * 4 + r;
                    *(short*)(T + ml * 256 + ((nl * 2) ^ ((ml & 7) << 4))) =
                        f2bf((acc[mi][ni][r] + bv) * sc);
                }
            }
        __syncthreads();
        short* base = (which == 0) ? Q : Kb;
        const int row = tid >> 4, seg = tid & 15;
#pragma unroll
        for (int p = 0; p < 8; ++p) {
            int m = p * 16 + row;
            uint4v v = *(uint4v*)(T + m * 256 + ((seg * 16) ^ ((m & 7) << 4)));
            int gn = n0 + seg * 8 - which * 1024;          // 0..1023
            int hh2 = gn >> 6, d = gn & 63;
            *(uint4v*)&base[((size_t)hh2 * TT + (m0 + m)) * DH + d] = v;
        }
    } else {
        // tile [n][m] bf16, row = 256B; phys = n*256 + ((m*2) ^ ((n&7)<<4))
#pragma unroll
        for (int mi = 0; mi < 4; ++mi)
#pragma unroll
            for (int ni = 0; ni < 4; ++ni) {
                int nl = wn * 64 + ni * 16 + l16;
                float bv = bias[n0 + nl];
                int ml0 = wm * 64 + mi * 16 + quad * 4;
                uint2 pk;
                pk.x = pk_rne(acc[mi][ni][0] + bv, acc[mi][ni][1] + bv);
                pk.y = pk_rne(acc[mi][ni][2] + bv, acc[mi][ni][3] + bv);
                *(uint2*)(T + nl * 256 + ((ml0 * 2) ^ ((nl & 7) << 4))) = pk;
            }
        __syncthreads();
        const int row = tid >> 4, seg = tid & 15;
#pragma unroll
        for (int p = 0; p < 8; ++p) {
            int n = p * 16 + row;
            uint4v v = *(uint4v*)(T + n * 256 + ((seg * 16) ^ ((n & 7) << 4)));
            int gn = n0 + n - 2048;                        // 0..1023
            int hh2 = gn >> 6, d = gn & 63;
            *(uint4v*)&Vtg[((size_t)hh2 * DH + d) * TT + m0 + seg * 8] = v;
        }
    }
}

// ---------------- flash attention v13: R3 body, two paired tiles per block --------
// PLATEAU ACCEPTED at ~78-79us: R3 (4 blk/CU decaying) == R8 (2 blk/CU flat) ->
// per-CU throughput saturates; per-iteration serial latency is the limit.
// DO NOT permute head<->block mapping (R1: per-XCD L2 head affinity ~15%).
__device__ __forceinline__ void attn_tile(const short* __restrict__ Qp,
                                          const short* __restrict__ Kp,
                                          const short* __restrict__ Vp,
                                          short* __restrict__ Ob,
                                          int h, int qi,
                                          int tid, int lane, int w, int quad, int l16,
                                          short* __restrict__ Ps0,
                                          float (*wl)[64], float* lsum) {
    const int q0 = qi * 64;
    const int nk = (qi >> 1) + 1;

    short8 aq[4][2];
#pragma unroll
    for (int qg = 0; qg < 4; ++qg)
#pragma unroll
        for (int ss = 0; ss < 2; ++ss)
            aq[qg][ss] = *(const short8*)&Qp[(size_t)(q0 + qg * 16 + l16) * DH + ss * 32 + quad * 8];

    floatx4 accO[4] = {};
    float l_part[4] = {0.f, 0.f, 0.f, 0.f};
    int buf = 0;

    short8 kf[2][2];
#pragma unroll
    for (int mi = 0; mi < 2; ++mi)
#pragma unroll
        for (int ss = 0; ss < 2; ++ss)
            kf[mi][ss] = *(const short8*)&Kp[(size_t)(w * 32 + mi * 16 + l16) * DH + ss * 32 + quad * 8];

    for (int ki = 0; ki < nk; ++ki) {
        const int k0 = ki * 128;
        const bool masked = (ki == nk - 1);

        floatx4 accS[2][4] = {};
        __builtin_amdgcn_s_setprio(1);
#pragma unroll
        for (int mi = 0; mi < 2; ++mi)
#pragma unroll
            for (int ss = 0; ss < 2; ++ss)
#pragma unroll
                for (int qg = 0; qg < 4; ++qg)
                    accS[mi][qg] = __builtin_amdgcn_mfma_f32_16x16x32_bf16(kf[mi][ss], aq[qg][ss], accS[mi][qg], 0, 0, 0);
        __builtin_amdgcn_s_setprio(0);

        short* Pb = Ps0 + buf * (64 * 136);
#pragma unroll
        for (int mi = 0; mi < 2; ++mi) {
            const int kbase = k0 + w * 32 + mi * 16 + quad * 4;
#pragma unroll
            for (int qg = 0; qg < 4; ++qg) {
                float pv[4];
#pragma unroll
                for (int r = 0; r < 4; ++r) {
                    float e = __builtin_amdgcn_exp2f(accS[mi][qg][r]);
                    if (masked)
                        e = (kbase + r <= q0 + qg * 16 + l16) ? e : 0.f;
                    pv[r] = e;
                    l_part[qg] += e;
                }
                uint2 pk;
                pk.x = pk_trunc(pv[0], pv[1]);
                pk.y = pk_trunc(pv[2], pv[3]);
                *(uint2*)&Pb[(qg * 16 + l16) * 136 + w * 32 + mi * 16 + quad * 4] = pk;
            }
        }

        short8 vf[4];
#pragma unroll
        for (int ks = 0; ks < 4; ++ks)
            vf[ks] = *(const short8*)&Vp[(size_t)(w * 16 + l16) * TT + k0 + ks * 32 + quad * 8];

        short8 kfn[2][2];
        if (ki + 1 < nk) {
            const int kn0 = k0 + 128;
#pragma unroll
            for (int mi = 0; mi < 2; ++mi)
#pragma unroll
                for (int ss = 0; ss < 2; ++ss)
                    kfn[mi][ss] = *(const short8*)&Kp[(size_t)(kn0 + w * 32 + mi * 16 + l16) * DH + ss * 32 + quad * 8];
        }

        asm volatile("s_waitcnt lgkmcnt(0)" ::: "memory");
        __builtin_amdgcn_s_barrier();
        asm volatile("" ::: "memory");

        __builtin_amdgcn_s_setprio(1);
#pragma unroll
        for (int qg = 0; qg < 4; ++qg)
#pragma unroll
            for (int ks = 0; ks < 4; ++ks) {
                short8 ap = *(const short8*)&Pb[(qg * 16 + l16) * 136 + ks * 32 + quad * 8];
                accO[qg] = __builtin_amdgcn_mfma_f32_16x16x32_bf16(ap, vf[ks], accO[qg], 0, 0, 0);
            }
        __builtin_amdgcn_s_setprio(0);

#pragma unroll
        for (int mi = 0; mi < 2; ++mi)
#pragma unroll
            for (int ss = 0; ss < 2; ++ss)
                kf[mi][ss] = kfn[mi][ss];
        buf ^= 1;
    }

#pragma unroll
    for (int qg = 0; qg < 4; ++qg) {
        float lr = l_part[qg];
        lr += __shfl_xor(lr, 16, 64);
        lr += __shfl_xor(lr, 32, 64);
        if (lane < 16) wl[w][qg * 16 + lane] = lr;
    }
    __syncthreads();
    if (tid < 64) lsum[tid] = wl[0][tid] + wl[1][tid] + wl[2][tid] + wl[3][tid];
    __syncthreads();

#pragma unroll
    for (int qg = 0; qg < 4; ++qg) {
#pragma unroll
        for (int r = 0; r < 4; ++r) {
            int q = qg * 16 + quad * 4 + r;
            float o = accO[qg][r] / lsum[q];
            Ob[(size_t)(q0 + q) * CC + h * DH + w * 16 + l16] = f2bf(o);
        }
    }
}

__global__ __launch_bounds__(256) void k_attn(const short* __restrict__ Qh,
                                              const short* __restrict__ Kh,
                                              const short* __restrict__ VhT,
                                              short* __restrict__ Ob) {
    const int h = blockIdx.x;
    const int y = blockIdx.y;          // 0..31; tiles (63-y) + (y): 33 iters total
    const int tid = threadIdx.x, lane = tid & 63, w = tid >> 6;
    const int quad = lane >> 4, l16 = lane & 15;

    __shared__ __attribute__((aligned(16))) short Ps[2][64 * 136];
    __shared__ float wl[4][64];
    __shared__ float lsum[64];

    const short* Qp = Qh + (size_t)h * TT * DH;
    const short* Kp = Kh + (size_t)h * TT * DH;
    const short* Vp = VhT + (size_t)h * DH * TT;

    attn_tile(Qp, Kp, Vp, Ob, h, 63 - y, tid, lane, w, quad, l16, &Ps[0][0], wl, lsum);
    attn_tile(Qp, Kp, Vp, Ob, h, y,      tid, lane, w, quad, l16, &Ps[0][0], wl, lsum);
}

// ---------------- GEMM2 v2: out = Ob @ w_proj + b, 64x128 tiles -------------------
// 512 blocks = 2/CU (R9: -4us vs 1 blk/CU).
__global__ __launch_bounds__(256) void k_gemm_proj(const short* __restrict__ A,
                                                   const short* __restrict__ Bt,
                                                   const float* __restrict__ bias,
                                                   float* __restrict__ out) {
    const int m0 = blockIdx.y * 64;
    const int n0 = blockIdx.x * 128;
    __shared__ __attribute__((aligned(16))) short As[2][64 * 32];
    __shared__ __attribute__((aligned(16))) short Bs[2][128 * 32];
    const int tid = threadIdx.x;
    const int lane = tid & 63;
    const int w = tid >> 6;
    const int quad = lane >> 4;
    const int l16 = lane & 15;

    const int r0 = tid >> 2, c0 = (tid & 3) * 8;
    const short* pA[2]; const short* pB[2][2];
    short* lA[2]; short* lB[2][2];
#pragma unroll
    for (int hh = 0; hh < 2; ++hh) {
        pA[hh] = A + (size_t)(m0 + r0) * CC + hh * 32 + c0;
        lA[hh] = &As[hh][w * 512];
#pragma unroll
        for (int it = 0; it < 2; ++it) {
            pB[it][hh] = Bt + (size_t)(n0 + it * 64 + r0) * CC + hh * 32 + c0;
            lB[it][hh] = &Bs[hh][(it * 256 + w * 64) * 8];
        }
    }

    floatx4 acc[4][2] = {};
    for (int kb = 0; kb < CC; kb += 64) {
        __syncthreads();
#pragma unroll
        for (int hh = 0; hh < 2; ++hh) {
            gload_lds16(pA[hh] + kb, lA[hh]);
#pragma unroll
            for (int it = 0; it < 2; ++it)
                gload_lds16(pB[it][hh] + kb, lB[it][hh]);
        }
        __syncthreads();
#pragma unroll
        for (int kk = 0; kk < 2; ++kk) {
            short8 af[4], bf[2];
#pragma unroll
            for (int mi = 0; mi < 4; ++mi)
                af[mi] = *(const short8*)&As[kk][(mi * 16 + l16) * 32 + quad * 8];
#pragma unroll
            for (int ni = 0; ni < 2; ++ni)
                bf[ni] = *(const short8*)&Bs[kk][(w * 32 + ni * 16 + l16) * 32 + quad * 8];
#pragma unroll
            for (int mi = 0; mi < 4; ++mi)
#pragma unroll
                for (int ni = 0; ni < 2; ++ni)
                    acc[mi][ni] = __builtin_amdgcn_mfma_f32_16x16x32_bf16(af[mi], bf[ni], acc[mi][ni], 0, 0, 0);
        }
    }
#pragma unroll
    for (int mi = 0; mi < 4; ++mi) {
#pragma unroll
        for (int ni = 0; ni < 2; ++ni) {
            int gm = m0 + mi * 16 + quad * 4;
            int gn = n0 + w * 32 + ni * 16 + l16;
            float bv = bias[gn];
#pragma unroll
            for (int r = 0; r < 4; ++r)
                out[(size_t)(gm + r) * CC + gn] = acc[mi][ni][r] + bv;
        }
    }
}

extern "C" void kernel_launch(void* const* d_in, const int* in_sizes, int n_in,
                              void* d_out, int out_size, void* d_ws, size_t ws_size,
                              hipStream_t stream) {
    const float* x      = (const float*)d_in[0];
    const float* w_qkv  = (const float*)d_in[1];
    const float* b_qkv  = (const float*)d_in[2];
    const float* w_proj = (const float*)d_in[3];
    const float* b_proj = (const float*)d_in[4];
    float* out = (float*)d_out;
    char* ws = (char*)d_ws;

    short* xb     = (short*)(ws);                       // 8388608 B
    short* wqkvT  = (short*)(ws + 8388608);             // 6291456 B
    short* wprojT = (short*)(ws + 14680064);            // 2097152 B
    short* Qh     = (short*)(ws + 16777216);            // 8388608 B
    short* Kh     = (short*)(ws + 25165824);
    short* VhT    = (short*)(ws + 33554432);            // [H,64,T]
    short* Ob     = (short*)(ws + 41943040);
    // total 50331648 B (48 MB)

    k_prep<<<8192, 256, 0, stream>>>(x, xb, w_qkv, wqkvT, w_proj, wprojT);
    k_gemm_qkv<<<dim3(N3C / 128, TT / 128), 256, 0, stream>>>(xb, wqkvT, b_qkv, Qh, Kh, VhT);
    k_attn<<<dim3(NHEAD, 32), 256, 0, stream>>>(Qh, Kh, VhT, Ob);
    k_gemm_proj<<<dim3(CC / 128, TT / 64), 256, 0, stream>>>(Ob, wprojT, b_proj, out);
}

// Round 11
// 206.640 us; speedup vs baseline: 1.4242x; 1.0063x over previous
//
#include <hip/hip_runtime.h>
#include <hip/hip_bf16.h>

#define TT 4096
#define CC 1024
#define NHEAD 16
#define DH 64
#define N3C 3072

typedef __attribute__((ext_vector_type(8))) short short8;
typedef __attribute__((ext_vector_type(4))) float floatx4;
typedef __attribute__((ext_vector_type(16))) float floatx16;
typedef __attribute__((ext_vector_type(4))) unsigned int uint4v;

// Q pre-scale: 1/sqrt(64) * log2(e)  (softmax in exp2 domain, m=0 fixed)
#define QSCALE 0.18033688011112042f

__device__ __forceinline__ short f2bf(float f) {
    union { __hip_bfloat16 h; short s; } u;
    u.h = __float2bfloat16(f);
    return u.s;
}

// async global->LDS 16B per lane; LDS dest = wave-uniform base + lane*16
__device__ __forceinline__ void gload_lds16(const void* g, void* l) {
    __builtin_amdgcn_global_load_lds(
        (const __attribute__((address_space(1))) unsigned int*)(unsigned long long)g,
        (__attribute__((address_space(3))) unsigned int*)(unsigned int)(unsigned long long)l,
        16, 0, 0);
}

// pack two fp32 -> bf16x2 by truncation (1 v_perm) — used only for attn P
__device__ __forceinline__ unsigned pk_trunc(float lo, float hi) {
    return __builtin_amdgcn_perm(__float_as_uint(hi), __float_as_uint(lo), 0x07060302u);
}

// pack two fp32 -> bf16x2 with RNE rounding (numerics identical to f2bf path)
__device__ __forceinline__ unsigned pk_rne(float lo, float hi) {
    unsigned a = (unsigned short)f2bf(lo);
    unsigned b = (unsigned short)f2bf(hi);
    return a | (b << 16);
}

// ---------------- fused prep: cvt x->bf16, transpose both weights ----------------
__device__ __forceinline__ void tr_body(const float* __restrict__ in, short* __restrict__ out,
                                        int K, int N, int bx, int by, int tid, float (*tile)[33]) {
    int nt = bx * 32, kt = by * 32;
    int tx = tid & 31, ty = tid >> 5;
#pragma unroll
    for (int i = 0; i < 32; i += 8)
        tile[ty + i][tx] = in[(size_t)(kt + ty + i) * N + nt + tx];
    __syncthreads();
#pragma unroll
    for (int i = 0; i < 32; i += 8)
        out[(size_t)(nt + ty + i) * K + kt + tx] = f2bf(tile[tx][ty + i]);
}

__global__ void k_prep(const float* __restrict__ x, short* __restrict__ xb,
                       const float* __restrict__ w_qkv, short* __restrict__ wqkvT,
                       const float* __restrict__ w_proj, short* __restrict__ wprojT) {
    __shared__ float tile[32][33];
    int id = blockIdx.x;
    int tid = threadIdx.x;
    if (id < 4096) {
        int i = (id * 256 + tid) * 4;
        float4 v = *(const float4*)&x[i];
        short4 r;
        r.x = f2bf(v.x); r.y = f2bf(v.y); r.z = f2bf(v.z); r.w = f2bf(v.w);
        *(short4*)&xb[i] = r;
    } else if (id < 4096 + 3072) {
        int r = id - 4096;
        tr_body(w_qkv, wqkvT, CC, N3C, r % 96, r / 96, tid, tile);
    } else {
        int r = id - 7168;
        tr_body(w_proj, wprojT, CC, CC, r & 31, r >> 5, tid, tile);
    }
}

// ---------------- GEMM1 v2: qkv = x @ w_qkv + b, LDS re-layout epilogue -----------
__global__ __launch_bounds__(256) void k_gemm_qkv(const short* __restrict__ A,
                                                  const short* __restrict__ Bt,
                                                  const float* __restrict__ bias,
                                                  short* __restrict__ Q,
                                                  short* __restrict__ Kb,
                                                  short* __restrict__ Vtg) {
    const int m0 = blockIdx.y * 128;
    const int n0 = blockIdx.x * 128;
    __shared__ __attribute__((aligned(16))) short Sbuf[4][128 * 32];  // As=0/1, Bs=2/3
    const int tid = threadIdx.x;
    const int lane = tid & 63;
    const int w = tid >> 6;
    const int wm = w >> 1, wn = w & 1;
    const int quad = lane >> 4;
    const int l16 = lane & 15;

    const int r0 = tid >> 2, c0 = (tid & 3) * 8;
    const short* pA[2][2]; const short* pB[2][2];
    short* lA[2][2]; short* lB[2][2];
#pragma unroll
    for (int it = 0; it < 2; ++it)
#pragma unroll
        for (int hh = 0; hh < 2; ++hh) {
            pA[it][hh] = A + (size_t)(m0 + it * 64 + r0) * CC + hh * 32 + c0;
            pB[it][hh] = Bt + (size_t)(n0 + it * 64 + r0) * CC + hh * 32 + c0;
            lA[it][hh] = &Sbuf[hh][(it * 256 + w * 64) * 8];
            lB[it][hh] = &Sbuf[2 + hh][(it * 256 + w * 64) * 8];
        }

    floatx4 acc[4][4] = {};
    for (int kb = 0; kb < CC; kb += 64) {
        __syncthreads();
#pragma unroll
        for (int it = 0; it < 2; ++it)
#pragma unroll
            for (int hh = 0; hh < 2; ++hh) {
                gload_lds16(pA[it][hh] + kb, lA[it][hh]);
                gload_lds16(pB[it][hh] + kb, lB[it][hh]);
            }
        __syncthreads();
#pragma unroll
        for (int kk = 0; kk < 2; ++kk) {
            short8 af[4], bf[4];
#pragma unroll
            for (int mi = 0; mi < 4; ++mi)
                af[mi] = *(const short8*)&Sbuf[kk][(wm * 64 + mi * 16 + l16) * 32 + quad * 8];
#pragma unroll
            for (int ni = 0; ni < 4; ++ni)
                bf[ni] = *(const short8*)&Sbuf[2 + kk][(wn * 64 + ni * 16 + l16) * 32 + quad * 8];
#pragma unroll
            for (int mi = 0; mi < 4; ++mi)
#pragma unroll
                for (int ni = 0; ni < 4; ++ni)
                    acc[mi][ni] = __builtin_amdgcn_mfma_f32_16x16x32_bf16(af[mi], bf[ni], acc[mi][ni], 0, 0, 0);
        }
    }

    // ---- epilogue: acc -> LDS tile (swizzled) -> coalesced 16B stores ----
    __syncthreads();                    // staging LDS dead; safe to reuse
    char* T = (char*)&Sbuf[0][0];
    const int which = n0 >> 10;         // block-uniform: 0=Q, 1=K, 2=V

    if (which < 2) {
        const float sc = (which == 0) ? QSCALE : 1.0f;
#pragma unroll
        for (int mi = 0; mi < 4; ++mi)
#pragma unroll
            for (int ni = 0; ni < 4; ++ni) {
                int nl = wn * 64 + ni * 16 + l16;
                float bv = bias[n0 + nl];
#pragma unroll
                for (int r = 0; r < 4; ++r) {
                    int ml = wm * 64 + mi * 16 + quad * 4 + r;
                    *(short*)(T + ml * 256 + ((nl * 2) ^ ((ml & 7) << 4))) =
                        f2bf((acc[mi][ni][r] + bv) * sc);
                }
            }
        __syncthreads();
        short* base = (which == 0) ? Q : Kb;
        const int row = tid >> 4, seg = tid & 15;
#pragma unroll
        for (int p = 0; p < 8; ++p) {
            int m = p * 16 + row;
            uint4v v = *(uint4v*)(T + m * 256 + ((seg * 16) ^ ((m & 7) << 4)));
            int gn = n0 + seg * 8 - which * 1024;          // 0..1023
            int hh2 = gn >> 6, d = gn & 63;
            *(uint4v*)&base[((size_t)hh2 * TT + (m0 + m)) * DH + d] = v;
        }
    } else {
#pragma unroll
        for (int mi = 0; mi < 4; ++mi)
#pragma unroll
            for (int ni = 0; ni < 4; ++ni) {
                int nl = wn * 64 + ni * 16 + l16;
                float bv = bias[n0 + nl];
                int ml0 = wm * 64 + mi * 16 + quad * 4;
                uint2 pk;
                pk.x = pk_rne(acc[mi][ni][0] + bv, acc[mi][ni][1] + bv);
                pk.y = pk_rne(acc[mi][ni][2] + bv, acc[mi][ni][3] + bv);
                *(uint2*)(T + nl * 256 + ((ml0 * 2) ^ ((nl & 7) << 4))) = pk;
            }
        __syncthreads();
        const int row = tid >> 4, seg = tid & 15;
#pragma unroll
        for (int p = 0; p < 8; ++p) {
            int n = p * 16 + row;
            uint4v v = *(uint4v*)(T + n * 256 + ((seg * 16) ^ ((n & 7) << 4)));
            int gn = n0 + n - 2048;                        // 0..1023
            int hh2 = gn >> 6, d = gn & 63;
            *(uint4v*)&Vtg[((size_t)hh2 * DH + d) * TT + m0 + seg * 8] = v;
        }
    }
}

// ---------------- flash attention v14: LDS-staged K/V + in-register P -------------
// R3-family plateau (~78us) diagnosed: P LDS round-trip (8-way-conflict reads,
// barrier convoy) + K/V GLOBAL GATHERS (V^T rows 8KB-strided -> up to 64 cache
// lines per load instruction, L2 service on the critical path). R6/R7 removed
// the P round-trip but kept uncovered per-wave gathers (2600cy/step).
// v14 combines the lessons:
//  - K/V tiles (KVBLK=64, D=64) staged into LDS via global_load_lds, async,
//    one tile ahead, amortized over 4 warps; drained by a cheap vmcnt(0) after
//    ~600cy of compute. XOR-swizzled via PRE-SWIZZLED GLOBAL SOURCE (linear LDS
//    dest — rule #21), reads swizzled: unit' = unit ^ (row&7) -> <=4-way.
//  - P stays in registers: swapped QK^T (mfma_32x32x16, S^T[k][q], q=lane&31,
//    k-rows (r&3)+8(r>>2)+4hi — R6 harness-verified) + pk_trunc/permlane32_swap
//    relayout to the PV A-operand.
//  - 4 warps x 32 q-rows = 128-q tile; warp skips fully-masked tiles (<=1 tile
//    skew). Block runs paired q-tiles (31-y, y) SEQUENTIALLY = uniform 66
//    tiles/block; grid (16,16)=256 blocks=1/CU; bid%8=h%8 (XCD affinity, R1).
//  - One barrier + one vmcnt(0) per tile; no Ps, no lgkm round-trip.
// Failure rule: if >= 77us, revert to R10 and close.
__device__ __forceinline__ void stage_kv(const short* __restrict__ Kp,
                                         const short* __restrict__ Vp,
                                         short* lk, short* lv,
                                         int k0, int w, int lane) {
    const int p = lane & 7;
    const int rl = lane >> 3;                  // 0..7
#pragma unroll
    for (int i = 0; i < 2; ++i) {
        const int R = w * 16 + i * 8 + rl;     // row staged by this lane
        const int u = p ^ (R & 7);             // logical 16B unit for phys slot p
        gload_lds16(Kp + (size_t)(k0 + R) * DH + u * 8, lk + (w * 16 + i * 8) * 64);
        gload_lds16(Vp + (size_t)R * TT + k0 + u * 8,   lv + (w * 16 + i * 8) * 64);
    }
}

__device__ __forceinline__ void attn_qtile(const short* __restrict__ Qp,
                                           const short* __restrict__ Kp,
                                           const short* __restrict__ Vp,
                                           short* __restrict__ Ob,
                                           int h, int qi,
                                           int w, int lane, int l31, int hi,
                                           short* ldsK, short* ldsV) {
    const int qs = qi * 128 + w * 32;          // this warp's first q row
    const int nk = 2 * qi + 2;                 // 64-wide k-tiles for the block

    // Q B-frags (persistent): B[d][q=l31], 8 consecutive d per lane
    short8 bq[4];
#pragma unroll
    for (int st = 0; st < 4; ++st)
        bq[st] = *(const short8*)&Qp[(size_t)(qs + l31) * DH + st * 16 + hi * 8];

    floatx16 accO0 = {}, accO1 = {};
    float l_acc = 0.f;

    // stage tile 0 into buf 0
    stage_kv(Kp, Vp, ldsK, ldsV, 0, w, lane);
    asm volatile("s_waitcnt vmcnt(0)" ::: "memory");
    __builtin_amdgcn_s_barrier();
    asm volatile("" ::: "memory");

    int buf = 0;
    for (int t = 0; t < nk; ++t) {
        const int k0 = t * 64;
        // stage next tile into the other buffer (async; drained before barrier)
        if (t + 1 < nk)
            stage_kv(Kp, Vp, ldsK + (buf ^ 1) * 4096, ldsV + (buf ^ 1) * 4096,
                     k0 + 64, w, lane);

        const bool skip = (k0 > qs + 31);      // tile fully above causal diagonal
        if (!skip) {
            const short* lk = ldsK + buf * 4096;
            const short* lv = ldsV + buf * 4096;
            const bool masked = (k0 + 63 > qs);
            const int qg = qs + l31;

            // K A-frags from LDS (swizzled read)
            short8 ak[2][4];
#pragma unroll
            for (int sub = 0; sub < 2; ++sub)
#pragma unroll
                for (int st = 0; st < 4; ++st)
                    ak[sub][st] = *(const short8*)&lk[(sub * 32 + l31) * 64 +
                                                     (((st * 2 + hi) ^ (l31 & 7)) * 8)];

            // S^T[64k][32q] in two 32-k halves
            floatx16 s0 = {}, s1 = {};
#pragma unroll
            for (int st = 0; st < 4; ++st) {
                s0 = __builtin_amdgcn_mfma_f32_32x32x16_bf16(ak[0][st], bq[st], s0, 0, 0, 0);
                s1 = __builtin_amdgcn_mfma_f32_32x32x16_bf16(ak[1][st], bq[st], s1, 0, 0, 0);
            }

#pragma unroll
            for (int sub = 0; sub < 2; ++sub) {
                float p[16];
#pragma unroll
                for (int r = 0; r < 16; ++r)
                    p[r] = __builtin_amdgcn_exp2f(sub == 0 ? s0[r] : s1[r]);
                if (masked) {
#pragma unroll
                    for (int r = 0; r < 16; ++r) {
                        int kg = k0 + sub * 32 + (r & 3) + 8 * (r >> 2) + 4 * hi;
                        p[r] = (kg <= qg) ? p[r] : 0.f;
                    }
                }
                {   // shallow tree-sum into l
                    float t0 = (p[0] + p[1]) + (p[2] + p[3]);
                    float t1 = (p[4] + p[5]) + (p[6] + p[7]);
                    float t2 = (p[8] + p[9]) + (p[10] + p[11]);
                    float t3 = (p[12] + p[13]) + (p[14] + p[15]);
                    l_acc += (t0 + t1) + (t2 + t3);
                }
                // T12 relayout: D-layout -> PV A-operand (P[q=l31][k 8-consec])
                unsigned pa[8];
                pa[0] = pk_trunc(p[0], p[1]);   pa[1] = pk_trunc(p[2], p[3]);
                pa[2] = pk_trunc(p[4], p[5]);   pa[3] = pk_trunc(p[6], p[7]);
                pa[4] = pk_trunc(p[8], p[9]);   pa[5] = pk_trunc(p[10], p[11]);
                pa[6] = pk_trunc(p[12], p[13]); pa[7] = pk_trunc(p[14], p[15]);
                asm("v_permlane32_swap_b32 %0, %1" : "+v"(pa[0]), "+v"(pa[2]));
                asm("v_permlane32_swap_b32 %0, %1" : "+v"(pa[1]), "+v"(pa[3]));
                asm("v_permlane32_swap_b32 %0, %1" : "+v"(pa[4]), "+v"(pa[6]));
                asm("v_permlane32_swap_b32 %0, %1" : "+v"(pa[5]), "+v"(pa[7]));
                uint4v a0v = {pa[0], pa[1], pa[2], pa[3]};   // k sub*32+0..15
                uint4v a1v = {pa[4], pa[5], pa[6], pa[7]};   // k sub*32+16..31
                short8 A0 = __builtin_bit_cast(short8, a0v);
                short8 A1 = __builtin_bit_cast(short8, a1v);

                // V B-frags from LDS (swizzled read); rows d = db*32+l31
                short8 vf00 = *(const short8*)&lv[(l31) * 64 +
                                                  (((sub * 4 + hi) ^ (l31 & 7)) * 8)];
                short8 vf01 = *(const short8*)&lv[(l31) * 64 +
                                                  (((sub * 4 + 2 + hi) ^ (l31 & 7)) * 8)];
                short8 vf10 = *(const short8*)&lv[(32 + l31) * 64 +
                                                  (((sub * 4 + hi) ^ (l31 & 7)) * 8)];
                short8 vf11 = *(const short8*)&lv[(32 + l31) * 64 +
                                                  (((sub * 4 + 2 + hi) ^ (l31 & 7)) * 8)];

                accO0 = __builtin_amdgcn_mfma_f32_32x32x16_bf16(A0, vf00, accO0, 0, 0, 0);
                accO0 = __builtin_amdgcn_mfma_f32_32x32x16_bf16(A1, vf01, accO0, 0, 0, 0);
                accO1 = __builtin_amdgcn_mfma_f32_32x32x16_bf16(A0, vf10, accO1, 0, 0, 0);
                accO1 = __builtin_amdgcn_mfma_f32_32x32x16_bf16(A1, vf11, accO1, 0, 0, 0);
            }
        }

        // own stage loads landed (issued ~600cy ago); barrier publishes both bufs
        asm volatile("s_waitcnt vmcnt(0)" ::: "memory");
        __builtin_amdgcn_s_barrier();
        asm volatile("" ::: "memory");
        buf ^= 1;
    }

    // l: halves (hi=0/1) hold complementary k-rows for q=l31
    l_acc += __shfl_xor(l_acc, 32, 64);
    float inv = __builtin_amdgcn_rcpf(l_acc);

    // epilogue: accO row q = (r&3)+8(r>>2)+4hi, col d = l31 (+32 for accO1)
#pragma unroll
    for (int r = 0; r < 16; ++r) {
        int qr = (r & 3) + 8 * (r >> 2) + 4 * hi;   // < 32
        float iv = __shfl(inv, qr, 64);
        int qg = qs + qr;
        Ob[(size_t)qg * CC + h * DH + l31]      = f2bf(accO0[r] * iv);
        Ob[(size_t)qg * CC + h * DH + 32 + l31] = f2bf(accO1[r] * iv);
    }
}

__global__ __launch_bounds__(256) void k_attn(const short* __restrict__ Qh,
                                              const short* __restrict__ Kh,
                                              const short* __restrict__ VhT,
                                              short* __restrict__ Ob) {
    const int h = blockIdx.x;
    const int y = blockIdx.y;                  // 0..15; q-tiles (31-y) then (y)
    const int tid = threadIdx.x;
    const int w = tid >> 6;
    const int lane = tid & 63;
    const int l31 = lane & 31;
    const int hi = lane >> 5;

    __shared__ __attribute__((aligned(16))) short ldsK[2][4096];
    __shared__ __attribute__((aligned(16))) short ldsV[2][4096];

    const short* Qp = Qh + (size_t)h * TT * DH;
    const short* Kp = Kh + (size_t)h * TT * DH;
    const short* Vp = VhT + (size_t)h * DH * TT;

    attn_qtile(Qp, Kp, Vp, Ob, h, 31 - y, w, lane, l31, hi, &ldsK[0][0], &ldsV[0][0]);
    attn_qtile(Qp, Kp, Vp, Ob, h, y,      w, lane, l31, hi, &ldsK[0][0], &ldsV[0][0]);
}

// ---------------- GEMM2 v2: out = Ob @ w_proj + b, 64x128 tiles -------------------
__global__ __launch_bounds__(256) void k_gemm_proj(const short* __restrict__ A,
                                                   const short* __restrict__ Bt,
                                                   const float* __restrict__ bias,
                                                   float* __restrict__ out) {
    const int m0 = blockIdx.y * 64;
    const int n0 = blockIdx.x * 128;
    __shared__ __attribute__((aligned(16))) short As[2][64 * 32];
    __shared__ __attribute__((aligned(16))) short Bs[2][128 * 32];
    const int tid = threadIdx.x;
    const int lane = tid & 63;
    const int w = tid >> 6;
    const int quad = lane >> 4;
    const int l16 = lane & 15;

    const int r0 = tid >> 2, c0 = (tid & 3) * 8;
    const short* pA[2]; const short* pB[2][2];
    short* lA[2]; short* lB[2][2];
#pragma unroll
    for (int hh = 0; hh < 2; ++hh) {
        pA[hh] = A + (size_t)(m0 + r0) * CC + hh * 32 + c0;
        lA[hh] = &As[hh][w * 512];
#pragma unroll
        for (int it = 0; it < 2; ++it) {
            pB[it][hh] = Bt + (size_t)(n0 + it * 64 + r0) * CC + hh * 32 + c0;
            lB[it][hh] = &Bs[hh][(it * 256 + w * 64) * 8];
        }
    }

    floatx4 acc[4][2] = {};
    for (int kb = 0; kb < CC; kb += 64) {
        __syncthreads();
#pragma unroll
        for (int hh = 0; hh < 2; ++hh) {
            gload_lds16(pA[hh] + kb, lA[hh]);
#pragma unroll
            for (int it = 0; it < 2; ++it)
                gload_lds16(pB[it][hh] + kb, lB[it][hh]);
        }
        __syncthreads();
#pragma unroll
        for (int kk = 0; kk < 2; ++kk) {
            short8 af[4], bf[2];
#pragma unroll
            for (int mi = 0; mi < 4; ++mi)
                af[mi] = *(const short8*)&As[kk][(mi * 16 + l16) * 32 + quad * 8];
#pragma unroll
            for (int ni = 0; ni < 2; ++ni)
                bf[ni] = *(const short8*)&Bs[kk][(w * 32 + ni * 16 + l16) * 32 + quad * 8];
#pragma unroll
            for (int mi = 0; mi < 4; ++mi)
#pragma unroll
                for (int ni = 0; ni < 2; ++ni)
                    acc[mi][ni] = __builtin_amdgcn_mfma_f32_16x16x32_bf16(af[mi], bf[ni], acc[mi][ni], 0, 0, 0);
        }
    }
#pragma unroll
    for (int mi = 0; mi < 4; ++mi) {
#pragma unroll
        for (int ni = 0; ni < 2; ++ni) {
            int gm = m0 + mi * 16 + quad * 4;
            int gn = n0 + w * 32 + ni * 16 + l16;
            float bv = bias[gn];
#pragma unroll
            for (int r = 0; r < 4; ++r)
                out[(size_t)(gm + r) * CC + gn] = acc[mi][ni][r] + bv;
        }
    }
}

extern "C" void kernel_launch(void* const* d_in, const int* in_sizes, int n_in,
                              void* d_out, int out_size, void* d_ws, size_t ws_size,
                              hipStream_t stream) {
    const float* x      = (const float*)d_in[0];
    const float* w_qkv  = (const float*)d_in[1];
    const float* b_qkv  = (const float*)d_in[2];
    const float* w_proj = (const float*)d_in[3];
    const float* b_proj = (const float*)d_in[4];
    float* out = (float*)d_out;
    char* ws = (char*)d_ws;

    short* xb     = (short*)(ws);                       // 8388608 B
    short* wqkvT  = (short*)(ws + 8388608);             // 6291456 B
    short* wprojT = (short*)(ws + 14680064);            // 2097152 B
    short* Qh     = (short*)(ws + 16777216);            // 8388608 B
    short* Kh     = (short*)(ws + 25165824);
    short* VhT    = (short*)(ws + 33554432);            // [H,64,T]
    short* Ob     = (short*)(ws + 41943040);
    // total 50331648 B (48 MB)

    k_prep<<<8192, 256, 0, stream>>>(x, xb, w_qkv, wqkvT, w_proj, wprojT);
    k_gemm_qkv<<<dim3(N3C / 128, TT / 128), 256, 0, stream>>>(xb, wqkvT, b_qkv, Qh, Kh, VhT);
    k_attn<<<dim3(NHEAD, 16), 256, 0, stream>>>(Qh, Kh, VhT, Ob);
    k_gemm_proj<<<dim3(CC / 128, TT / 64), 256, 0, stream>>>(Ob, wprojT, b_proj, out);
}